// Round 6
// baseline (225.819 us; speedup 1.0000x reference)
//
#include <hip/hip_runtime.h>

// ---------------------------------------------------------------------------
// MultiHeadSelfAttention: B=2, S=2048, D=1024, H=16, HD=64, fp32 in/out.
// cast/transpose -> fused QKV bf16 MFMA GEMM (BK=32 dbuf global_load_lds,
// XOR-swz, 32 KB LDS -> 4 blocks/CU) -> split-T flash attention (fixed-max
// softmax, 128-row Q blocks, mi=2) -> combine -> out projection GEMM (same
// BK=32 dbuf). All matmuls: mfma_f32_16x16x32_bf16, fp32 accum.
// GEMM swizzle (BK=32: rows are 32 shorts = 4 x 16B chunks): chunk c of row
// r holds global chunk c ^ (r&3) ^ ((r>>2)&3). Staging permutes the GLOBAL
// address (global_load_lds dest must be base+lane*16); reads permute too.
// Attn K/V swizzle (rows 64 shorts = 8 chunks): chunk c ^= (r&7).
// ---------------------------------------------------------------------------

typedef __bf16 bf16x8 __attribute__((ext_vector_type(8)));
typedef float  f32x4  __attribute__((ext_vector_type(4)));

#if __has_builtin(__builtin_amdgcn_exp2f)
#define EXPFN(x) __builtin_amdgcn_exp2f(x)
#define QSCALE (0.125f * 1.44269504088896f)   // fold log2(e) into Q
#else
#define EXPFN(x) __expf(x)
#define QSCALE 0.125f
#endif

#define LDKP 74  // Ps leading dim (shorts): odd dword stride breaks collisions

__device__ __forceinline__ unsigned short f2bf(float f) {
    unsigned int u = __float_as_uint(f);
    u += 0x7FFFu + ((u >> 16) & 1u);   // RNE; finite inputs
    return (unsigned short)(u >> 16);
}

// async global->LDS, 16B per lane; HW dest = firstlane(lptr) + lane*16.
__device__ __forceinline__ void gload16(const void* g, void* l) {
    __builtin_amdgcn_global_load_lds(
        (const __attribute__((address_space(1))) void*)g,
        (__attribute__((address_space(3))) void*)l, 16, 0, 0);
}

#define WAIT0_BARRIER() asm volatile("s_waitcnt vmcnt(0)\n\ts_barrier" ::: "memory")

// ---------------- cast X (fp32 -> bf16, same layout) -----------------------
__global__ __launch_bounds__(256) void cast_x_kernel(
    const float4* __restrict__ X, ushort4* __restrict__ Xb, int n4) {
    int i = blockIdx.x * 256 + threadIdx.x;
    if (i < n4) {
        float4 v = X[i];
        ushort4 o;
        o.x = f2bf(v.x); o.y = f2bf(v.y); o.z = f2bf(v.z); o.w = f2bf(v.w);
        Xb[i] = o;
    }
}

// ------------- transpose+cast weights: W[K][N] fp32 -> Wt[N][K] bf16 -------
__global__ __launch_bounds__(256) void transpose_w_kernel(
    const float* __restrict__ Wq, const float* __restrict__ Wk,
    const float* __restrict__ Wv, const float* __restrict__ Wo,
    unsigned short* __restrict__ Wt_all) {
    __shared__ float tile[32][33];
    const int z = blockIdx.z;
    const float* W = (z == 0) ? Wq : (z == 1) ? Wk : (z == 2) ? Wv : Wo;
    unsigned short* Wt = Wt_all + (size_t)z * 1024 * 1024;
    int c0 = blockIdx.x * 32, r0 = blockIdx.y * 32;
    int x = threadIdx.x, y = threadIdx.y;      // (32, 8)
    for (int j = 0; j < 32; j += 8)
        tile[y + j][x] = W[(r0 + y + j) * 1024 + c0 + x];
    __syncthreads();
    for (int j = 0; j < 32; j += 8)
        Wt[(c0 + y + j) * 1024 + r0 + x] = f2bf(tile[x][y + j]);
}

// ---------------- fused QKV GEMM (128x128 tile, BK=32, double-buffered) ----
// z=0: Q = X Wq^T + bq, scaled -> Qb[B,H,S,64]
// z=1: K = X Wk^T + bk        -> Kb[B,H,S,64]
// z=2: V^T = Wv^T X^T (+bv)   -> Vt[B,H,64,S]   (A/B roles swapped)
__global__ __launch_bounds__(256) void gemm_qkv_kernel(
    const unsigned short* __restrict__ Xb, const unsigned short* __restrict__ Wt_all,
    const float* __restrict__ bq, const float* __restrict__ bk,
    const float* __restrict__ bv,
    unsigned short* __restrict__ Qb, unsigned short* __restrict__ Kb,
    unsigned short* __restrict__ Vt) {
    const int z = blockIdx.z;
    const int x0 = blockIdx.x * 128;   // over 4096 (X rows)
    const int y0 = blockIdx.y * 128;   // over 1024 (W rows)

    const unsigned short* Ap;
    const unsigned short* Bp;
    if (z < 2) {
        Ap = Xb + (size_t)x0 * 1024;
        Bp = Wt_all + (size_t)z * 1024 * 1024 + (size_t)y0 * 1024;
    } else {
        Ap = Wt_all + (size_t)2 * 1024 * 1024 + (size_t)y0 * 1024;
        Bp = Xb + (size_t)x0 * 1024;
    }

    __shared__ __align__(16) unsigned short As[2][128 * 32];
    __shared__ __align__(16) unsigned short Bs[2][128 * 32];

    const int tid = threadIdx.x;
    const int lane = tid & 63, wave = tid >> 6;
    const int quad = lane >> 4, l15 = lane & 15;
    const int wrow = (wave >> 1) * 64, wcol = (wave & 1) * 64;

    f32x4 acc[4][4] = {};

    const int srow = lane >> 2;                     // 0..15
    const int ch4  = (lane & 3) * 8;                // natural chunk (shorts)
    const int sw4  = (((lane & 3) ^ (srow & 3) ^ ((srow >> 2) & 3))) * 8;
    const int rsw  = (l15 & 3) ^ ((l15 >> 2) & 3);  // read-side swizzle key

    // prologue: stage tile 0 into buffer 0
    #pragma unroll
    for (int c = 0; c < 2; c++) {
        int r = c * 64 + wave * 16 + srow;
        gload16(Ap + (size_t)r * 1024 + 0 + sw4, &As[0][r * 32 + ch4]);
        gload16(Bp + (size_t)r * 1024 + 0 + sw4, &Bs[0][r * 32 + ch4]);
    }

    for (int k = 0; k < 32; k++) {
        const int cur = k & 1, nxt = cur ^ 1;
        WAIT0_BARRIER();     // cur's loads landed; previous compute done
        if (k < 31) {
            int k0 = (k + 1) * 32;
            #pragma unroll
            for (int c = 0; c < 2; c++) {
                int r = c * 64 + wave * 16 + srow;
                gload16(Ap + (size_t)r * 1024 + k0 + sw4, &As[nxt][r * 32 + ch4]);
                gload16(Bp + (size_t)r * 1024 + k0 + sw4, &Bs[nxt][r * 32 + ch4]);
            }
        }
        bf16x8 af[4], bfr[4];
        #pragma unroll
        for (int i = 0; i < 4; i++)
            af[i] = *(const bf16x8*)&As[cur][(wrow + i * 16 + l15) * 32 +
                                             ((quad ^ rsw)) * 8];
        #pragma unroll
        for (int j = 0; j < 4; j++)
            bfr[j] = *(const bf16x8*)&Bs[cur][(wcol + j * 16 + l15) * 32 +
                                              ((quad ^ rsw)) * 8];
        #pragma unroll
        for (int i = 0; i < 4; i++)
            #pragma unroll
            for (int j = 0; j < 4; j++)
                acc[i][j] = __builtin_amdgcn_mfma_f32_16x16x32_bf16(
                    af[i], bfr[j], acc[i][j], 0, 0, 0);
    }

    // C/D layout: col=lane&15, row=quad*4+reg (m89/m91 verified)
    if (z < 2) {
        const float* bias = (z == 0) ? bq : bk;
        #pragma unroll
        for (int j = 0; j < 4; j++) {
            int col = y0 + wcol + j * 16 + l15;
            float bcol = bias[col];
            int h = col >> 6, d = col & 63;
            #pragma unroll
            for (int i = 0; i < 4; i++)
                #pragma unroll
                for (int r = 0; r < 4; r++) {
                    int row = x0 + wrow + i * 16 + quad * 4 + r;
                    int b = row >> 11, s = row & 2047;
                    float v = acc[i][j][r] + bcol;
                    if (z == 0)
                        Qb[(size_t)((b * 16 + h) * 2048 + s) * 64 + d] = f2bf(v * QSCALE);
                    else
                        Kb[(size_t)((b * 16 + h) * 2048 + s) * 64 + d] = f2bf(v);
                }
        }
    } else {
        #pragma unroll
        for (int i = 0; i < 4; i++)
            #pragma unroll
            for (int r = 0; r < 4; r++) {
                int rowd = y0 + wrow + i * 16 + quad * 4 + r;   // d_full 0..1023
                float brow = bv[rowd];
                #pragma unroll
                for (int j = 0; j < 4; j++) {
                    int colm = x0 + wcol + j * 16 + l15;        // m 0..4095
                    int b = colm >> 11, s = colm & 2047;
                    Vt[(size_t)(b * 1024 + rowd) * 2048 + s] = f2bf(acc[i][j][r] + brow);
                }
            }
    }
}

// ---------------- flash attention (fixed-max, split-T) ---------------------
// 128 Q rows/block, 4 waves x 32 rows (mi=2). l via MFMA ones-column.
// K/V staged with XOR swizzle; kf/vf read once per (j,kk), shared across mi.
__global__ __launch_bounds__(256) void attn_kernel(
    const unsigned short* __restrict__ Qb, const unsigned short* __restrict__ Kb,
    const unsigned short* __restrict__ Vt, unsigned short* __restrict__ Cc,
    float* __restrict__ Op, float* __restrict__ Lp, int tlen, int do_split) {
    const int bh = blockIdx.y;            // 0..31
    const int b = bh >> 4, h = bh & 15;
    const int q0 = blockIdx.x * 128;
    const int split = blockIdx.z;
    const int tbeg = split * tlen;

    const int tid = threadIdx.x;
    const int lane = tid & 63, wave = tid >> 6;
    const int quad = lane >> 4, l15 = lane & 15;

    __shared__ __align__(16) unsigned short Ks[64 * 64];
    __shared__ __align__(16) unsigned short Vs[64 * 64];
    __shared__ __align__(16) unsigned short Ps[4][32 * LDKP];

    const unsigned short* Qbh = Qb + (size_t)bh * 2048 * 64;
    const unsigned short* Kbh = Kb + (size_t)bh * 2048 * 64;
    const unsigned short* Vbh = Vt + (size_t)bh * 64 * 2048;

    // Q fragments in registers: A-layout m=lane&15, k=quad*8+j (m120)
    bf16x8 qa[2][2];
    #pragma unroll
    for (int mi = 0; mi < 2; mi++)
        #pragma unroll
        for (int kk = 0; kk < 2; kk++)
            qa[mi][kk] = *(const bf16x8*)&Qbh[
                (size_t)(q0 + wave * 32 + mi * 16 + l15) * 64 + kk * 32 + quad * 8];

    union { unsigned short us[8]; bf16x8 v; } ones_u;
    #pragma unroll
    for (int i = 0; i < 8; i++) ones_u.us[i] = 0x3F80;
    const bf16x8 onesv = ones_u.v;

    f32x4 o[2][4] = {};
    f32x4 ol[2] = {};

    const int srow = lane >> 3;                 // 0..7
    const int r0s = wave * 16 + srow;           // staging rows (2 per lane)
    const int ch8 = (lane & 7) * 8;
    const int swz = (((lane & 7) ^ srow)) * 8;  // row&7 == srow for both rows
    const int sw  = (l15 & 7);

    for (int ti = 0; ti < tlen; ti += 64) {
        const int t0 = tbeg + ti;
        __syncthreads();
        gload16(&Kbh[(size_t)(t0 + r0s) * 64 + swz],       &Ks[r0s * 64 + ch8]);
        gload16(&Kbh[(size_t)(t0 + r0s + 8) * 64 + swz],   &Ks[(r0s + 8) * 64 + ch8]);
        gload16(&Vbh[(size_t)r0s * 2048 + t0 + swz],       &Vs[r0s * 64 + ch8]);
        gload16(&Vbh[(size_t)(r0s + 8) * 2048 + t0 + swz], &Vs[(r0s + 8) * 64 + ch8]);
        asm volatile("s_waitcnt vmcnt(0)" ::: "memory");
        __syncthreads();

        // S = Q K^T (log2 domain), both mi share each kf read
        f32x4 sf[2][4] = {};
        #pragma unroll
        for (int j = 0; j < 4; j++)
            #pragma unroll
            for (int kk = 0; kk < 2; kk++) {
                bf16x8 kf = *(const bf16x8*)&Ks[(j * 16 + l15) * 64 +
                                                (((kk * 4 + quad) ^ sw)) * 8];
                sf[0][j] = __builtin_amdgcn_mfma_f32_16x16x32_bf16(qa[0][kk], kf, sf[0][j], 0, 0, 0);
                sf[1][j] = __builtin_amdgcn_mfma_f32_16x16x32_bf16(qa[1][kk], kf, sf[1][j], 0, 0, 0);
            }

        // P = exp2(S), truncated bf16, staged to LDS (C->A layout transform)
        #pragma unroll
        for (int mi = 0; mi < 2; mi++)
            #pragma unroll
            for (int j = 0; j < 4; j++)
                #pragma unroll
                for (int r = 0; r < 4; r++) {
                    float p = EXPFN(sf[mi][j][r]);
                    Ps[wave][(mi * 16 + quad * 4 + r) * LDKP + j * 16 + l15] =
                        (unsigned short)(__float_as_uint(p) >> 16);
                }

        asm volatile("s_waitcnt lgkmcnt(0)" ::: "memory");  // P visible wave-wide

        // O += P V ; l += P @ ones  (vf shared across mi)
        #pragma unroll
        for (int kk = 0; kk < 2; kk++) {
            bf16x8 pf0 = *(const bf16x8*)&Ps[wave][(l15) * LDKP + kk * 32 + quad * 8];
            bf16x8 pf1 = *(const bf16x8*)&Ps[wave][(16 + l15) * LDKP + kk * 32 + quad * 8];
            ol[0] = __builtin_amdgcn_mfma_f32_16x16x32_bf16(pf0, onesv, ol[0], 0, 0, 0);
            ol[1] = __builtin_amdgcn_mfma_f32_16x16x32_bf16(pf1, onesv, ol[1], 0, 0, 0);
            #pragma unroll
            for (int j = 0; j < 4; j++) {
                bf16x8 vf = *(const bf16x8*)&Vs[(j * 16 + l15) * 64 +
                                                (((kk * 4 + quad) ^ sw)) * 8];
                o[0][j] = __builtin_amdgcn_mfma_f32_16x16x32_bf16(pf0, vf, o[0][j], 0, 0, 0);
                o[1][j] = __builtin_amdgcn_mfma_f32_16x16x32_bf16(pf1, vf, o[1][j], 0, 0, 0);
            }
        }
    }

    if (do_split) {
        float* Opd = Op + (size_t)(split * 32 + bh) * 2048 * 64;
        float* Lpd = Lp + (size_t)(split * 32 + bh) * 2048;
        #pragma unroll
        for (int mi = 0; mi < 2; mi++)
            #pragma unroll
            for (int r = 0; r < 4; r++) {
                int s = q0 + wave * 32 + mi * 16 + quad * 4 + r;
                if (l15 == 0) Lpd[s] = ol[mi][r];
                #pragma unroll
                for (int j = 0; j < 4; j++)
                    Opd[(size_t)s * 64 + j * 16 + l15] = o[mi][j][r];
            }
    } else {
        #pragma unroll
        for (int mi = 0; mi < 2; mi++)
            #pragma unroll
            for (int r = 0; r < 4; r++) {
                float inv = 1.f / ol[mi][r];
                int s = q0 + wave * 32 + mi * 16 + quad * 4 + r;
                size_t row = (size_t)(b * 2048 + s);
                #pragma unroll
                for (int j = 0; j < 4; j++)
                    Cc[row * 1024 + h * 64 + j * 16 + l15] = f2bf(o[mi][j][r] * inv);
            }
    }
}

// ---------------- combine split partials -> Cc bf16 ------------------------
__global__ __launch_bounds__(256) void combine_kernel(
    const float4* __restrict__ Op, const float* __restrict__ Lp,
    unsigned short* __restrict__ Cc) {
    int idx = blockIdx.x * 256 + threadIdx.x;       // 0 .. 32*2048*16-1
    int d4 = idx & 15;
    int s = (idx >> 4) & 2047;
    int bh = idx >> 15;
    const size_t half4 = (size_t)32 * 2048 * 16;
    float4 a = Op[(size_t)idx], c = Op[half4 + (size_t)idx];
    float l = Lp[bh * 2048 + s] + Lp[32 * 2048 + bh * 2048 + s];
    float inv = 1.f / l;
    ushort4 o;
    o.x = f2bf((a.x + c.x) * inv); o.y = f2bf((a.y + c.y) * inv);
    o.z = f2bf((a.z + c.z) * inv); o.w = f2bf((a.w + c.w) * inv);
    int b = bh >> 4, h = bh & 15;
    *(ushort4*)&Cc[((size_t)(b * 2048 + s)) * 1024 + h * 64 + d4 * 4] = o;
}

// ---------------- output projection (128x128, BK=32 dbuf): Cc Wo^T + bo ----
__global__ __launch_bounds__(256) void gemm_out_kernel(
    const unsigned short* __restrict__ Cc, const unsigned short* __restrict__ Wot,
    const float* __restrict__ bo, float* __restrict__ out) {
    const int m0 = blockIdx.x * 128;   // over 4096
    const int n0 = blockIdx.y * 128;   // over 1024

    __shared__ __align__(16) unsigned short As[2][128 * 32];
    __shared__ __align__(16) unsigned short Bs[2][128 * 32];

    const int tid = threadIdx.x;
    const int lane = tid & 63, wave = tid >> 6;
    const int quad = lane >> 4, l15 = lane & 15;
    const int wrow = (wave >> 1) * 64, wcol = (wave & 1) * 64;

    f32x4 acc[4][4] = {};
    const int srow = lane >> 2;
    const int ch4  = (lane & 3) * 8;
    const int sw4  = (((lane & 3) ^ (srow & 3) ^ ((srow >> 2) & 3))) * 8;
    const int rsw  = (l15 & 3) ^ ((l15 >> 2) & 3);

    #pragma unroll
    for (int c = 0; c < 2; c++) {
        int r = c * 64 + wave * 16 + srow;
        gload16(Cc + (size_t)(m0 + r) * 1024 + sw4,  &As[0][r * 32 + ch4]);
        gload16(Wot + (size_t)(n0 + r) * 1024 + sw4, &Bs[0][r * 32 + ch4]);
    }

    for (int k = 0; k < 32; k++) {
        const int cur = k & 1, nxt = cur ^ 1;
        WAIT0_BARRIER();
        if (k < 31) {
            int k0 = (k + 1) * 32;
            #pragma unroll
            for (int c = 0; c < 2; c++) {
                int r = c * 64 + wave * 16 + srow;
                gload16(Cc + (size_t)(m0 + r) * 1024 + k0 + sw4,  &As[nxt][r * 32 + ch4]);
                gload16(Wot + (size_t)(n0 + r) * 1024 + k0 + sw4, &Bs[nxt][r * 32 + ch4]);
            }
        }
        bf16x8 af[4], bfr[4];
        #pragma unroll
        for (int i = 0; i < 4; i++)
            af[i] = *(const bf16x8*)&As[cur][(wrow + i * 16 + l15) * 32 +
                                             ((quad ^ rsw)) * 8];
        #pragma unroll
        for (int j = 0; j < 4; j++)
            bfr[j] = *(const bf16x8*)&Bs[cur][(wcol + j * 16 + l15) * 32 +
                                              ((quad ^ rsw)) * 8];
        #pragma unroll
        for (int i = 0; i < 4; i++)
            #pragma unroll
            for (int j = 0; j < 4; j++)
                acc[i][j] = __builtin_amdgcn_mfma_f32_16x16x32_bf16(
                    af[i], bfr[j], acc[i][j], 0, 0, 0);
    }

    #pragma unroll
    for (int j = 0; j < 4; j++) {
        int col = n0 + wcol + j * 16 + l15;
        float bcol = bo[col];
        #pragma unroll
        for (int i = 0; i < 4; i++)
            #pragma unroll
            for (int r = 0; r < 4; r++) {
                int row = m0 + wrow + i * 16 + quad * 4 + r;
                out[(size_t)row * 1024 + col] = acc[i][j][r] + bcol;
            }
    }
}

// ---------------------------------------------------------------------------
extern "C" void kernel_launch(void* const* d_in, const int* in_sizes, int n_in,
                              void* d_out, int out_size, void* d_ws, size_t ws_size,
                              hipStream_t stream) {
    const float* X  = (const float*)d_in[0];
    const float* Wq = (const float*)d_in[1];
    const float* bq = (const float*)d_in[2];
    const float* Wk = (const float*)d_in[3];
    const float* bk = (const float*)d_in[4];
    const float* Wv = (const float*)d_in[5];
    const float* bv = (const float*)d_in[6];
    const float* Wo = (const float*)d_in[7];
    const float* bo = (const float*)d_in[8];
    float* out = (float*)d_out;

    char* ws = (char*)d_ws;
    unsigned short* Xb = (unsigned short*)(ws);                    //  8 MB
    unsigned short* Wt = (unsigned short*)(ws + (8u  << 20));      //  8 MB (4 mats)
    unsigned short* Qb = (unsigned short*)(ws + (16u << 20));      //  8 MB
    unsigned short* Kb = (unsigned short*)(ws + (24u << 20));      //  8 MB
    unsigned short* Vt = (unsigned short*)(ws + (32u << 20));      //  8 MB
    unsigned short* Cc = (unsigned short*)(ws + (40u << 20));      //  8 MB
    float* Op = (float*)(ws + (48u << 20));                        // 32 MB
    float* Lp = (float*)(ws + (48u << 20) + 33554432u);            // 512 KB
    const bool use_split = ws_size >= ((size_t)(48u << 20) + 33554432u + 524288u);

    cast_x_kernel<<<4096, 256, 0, stream>>>((const float4*)X, (ushort4*)Xb, 1048576);
    transpose_w_kernel<<<dim3(32, 32, 4), dim3(32, 8), 0, stream>>>(Wq, Wk, Wv, Wo, Wt);
    gemm_qkv_kernel<<<dim3(32, 8, 3), 256, 0, stream>>>(Xb, Wt, bq, bk, bv, Qb, Kb, Vt);
    if (use_split) {
        attn_kernel<<<dim3(16, 32, 2), 256, 0, stream>>>(Qb, Kb, Vt, Cc, Op, Lp, 1024, 1);
        combine_kernel<<<4096, 256, 0, stream>>>((const float4*)Op, Lp, Cc);
    } else {
        attn_kernel<<<dim3(16, 32, 1), 256, 0, stream>>>(Qb, Kb, Vt, Cc, Op, Lp, 2048, 0);
    }
    gemm_out_kernel<<<dim3(32, 8), 256, 0, stream>>>(Cc, Wt + 3u * 1024 * 1024, bo, out);
}

// Round 7
// 217.723 us; speedup vs baseline: 1.0372x; 1.0372x over previous
//
#include <hip/hip_runtime.h>

// ---------------------------------------------------------------------------
// MultiHeadSelfAttention: B=2, S=2048, D=1024, H=16, HD=64, fp32 in/out.
// prep (cast X + transpose W, fused) -> fused QKV bf16 MFMA GEMM (BK=64 dbuf
// global_load_lds, XOR-swz) -> split-T flash attention (fixed-max softmax,
// 128-row Q blocks, K/V double-buffered) -> combine -> out projection GEMM.
// All matmuls: mfma_f32_16x16x32_bf16, fp32 accum.
// XOR swizzle: LDS rows are 64 shorts (128 B); chunk c (16 B) of row r holds
// global chunk c^(r&7). Staging permutes the GLOBAL address (global_load_lds
// dest must be base+lane*16); fragment reads apply the same permutation.
// ---------------------------------------------------------------------------

typedef __bf16 bf16x8 __attribute__((ext_vector_type(8)));
typedef float  f32x4  __attribute__((ext_vector_type(4)));

#if __has_builtin(__builtin_amdgcn_exp2f)
#define EXPFN(x) __builtin_amdgcn_exp2f(x)
#define QSCALE (0.125f * 1.44269504088896f)   // fold log2(e) into Q
#else
#define EXPFN(x) __expf(x)
#define QSCALE 0.125f
#endif

#define LDKP 74  // Ps leading dim (shorts): odd dword stride breaks collisions

__device__ __forceinline__ unsigned short f2bf(float f) {
    unsigned int u = __float_as_uint(f);
    u += 0x7FFFu + ((u >> 16) & 1u);   // RNE; finite inputs
    return (unsigned short)(u >> 16);
}

// async global->LDS, 16B per lane; HW dest = firstlane(lptr) + lane*16.
__device__ __forceinline__ void gload16(const void* g, void* l) {
    __builtin_amdgcn_global_load_lds(
        (const __attribute__((address_space(1))) void*)g,
        (__attribute__((address_space(3))) void*)l, 16, 0, 0);
}

#define WAIT0_BARRIER() asm volatile("s_waitcnt vmcnt(0)\n\ts_barrier" ::: "memory")

// ---------------- prep: cast X (z=4) + transpose/cast W (z=0..3) -----------
__global__ __launch_bounds__(256) void prep_kernel(
    const float* __restrict__ X, ushort4* __restrict__ Xb,
    const float* __restrict__ Wq, const float* __restrict__ Wk,
    const float* __restrict__ Wv, const float* __restrict__ Wo,
    unsigned short* __restrict__ Wt_all) {
    const int z = blockIdx.z;
    if (z == 4) {
        int base = (blockIdx.y * 32 + blockIdx.x) * 1024 + threadIdx.x;
        const float4* X4 = (const float4*)X;
        #pragma unroll
        for (int c = 0; c < 4; c++) {
            int i = base + c * 256;
            float4 v = X4[i];
            ushort4 o;
            o.x = f2bf(v.x); o.y = f2bf(v.y); o.z = f2bf(v.z); o.w = f2bf(v.w);
            Xb[i] = o;
        }
        return;
    }
    __shared__ float tile[32][33];
    const float* W = (z == 0) ? Wq : (z == 1) ? Wk : (z == 2) ? Wv : Wo;
    unsigned short* Wt = Wt_all + (size_t)z * 1024 * 1024;
    int c0 = blockIdx.x * 32, r0 = blockIdx.y * 32;
    int x = threadIdx.x & 31, y = threadIdx.x >> 5;   // (32, 8)
    for (int j = 0; j < 32; j += 8)
        tile[y + j][x] = W[(r0 + y + j) * 1024 + c0 + x];
    __syncthreads();
    for (int j = 0; j < 32; j += 8)
        Wt[(c0 + y + j) * 1024 + r0 + x] = f2bf(tile[x][y + j]);
}

// ---------------- fused QKV GEMM (128x128 tile, BK=64, double-buffered) ----
// z=0: Q = X Wq^T + bq, scaled -> Qb[B,H,S,64]
// z=1: K = X Wk^T + bk        -> Kb[B,H,S,64]
// z=2: V^T = Wv^T X^T (+bv)   -> Vt[B,H,64,S]   (A/B roles swapped)
__global__ __launch_bounds__(256) void gemm_qkv_kernel(
    const unsigned short* __restrict__ Xb, const unsigned short* __restrict__ Wt_all,
    const float* __restrict__ bq, const float* __restrict__ bk,
    const float* __restrict__ bv,
    unsigned short* __restrict__ Qb, unsigned short* __restrict__ Kb,
    unsigned short* __restrict__ Vt) {
    const int z = blockIdx.z;
    const int x0 = blockIdx.x * 128;   // over 4096 (X rows)
    const int y0 = blockIdx.y * 128;   // over 1024 (W rows)

    const unsigned short* Ap;
    const unsigned short* Bp;
    if (z < 2) {
        Ap = Xb + (size_t)x0 * 1024;
        Bp = Wt_all + (size_t)z * 1024 * 1024 + (size_t)y0 * 1024;
    } else {
        Ap = Wt_all + (size_t)2 * 1024 * 1024 + (size_t)y0 * 1024;
        Bp = Xb + (size_t)x0 * 1024;
    }

    __shared__ __align__(16) unsigned short As[2][128 * 64];
    __shared__ __align__(16) unsigned short Bs[2][128 * 64];

    const int tid = threadIdx.x;
    const int lane = tid & 63, wave = tid >> 6;
    const int quad = lane >> 4, l15 = lane & 15;
    const int wrow = (wave >> 1) * 64, wcol = (wave & 1) * 64;

    f32x4 acc[4][4] = {};

    const int srow = lane >> 3;            // 0..7
    const int ch8  = (lane & 7) * 8;       // natural chunk offset (shorts)
    const int swz  = (((lane & 7) ^ srow)) * 8;  // swizzled source chunk
    const int sw   = (l15 & 7);            // read-side row swizzle key

    // prologue: stage tile 0 into buffer 0
    #pragma unroll
    for (int c = 0; c < 4; c++) {
        int r = c * 32 + wave * 8 + srow;
        gload16(Ap + (size_t)r * 1024 + 0 + swz, &As[0][r * 64 + ch8]);
        gload16(Bp + (size_t)r * 1024 + 0 + swz, &Bs[0][r * 64 + ch8]);
    }

    for (int k = 0; k < 16; k++) {
        const int cur = k & 1, nxt = cur ^ 1;
        WAIT0_BARRIER();     // cur's loads landed everywhere; k-1 compute done
        if (k < 15) {
            int k0 = (k + 1) * 64;
            #pragma unroll
            for (int c = 0; c < 4; c++) {
                int r = c * 32 + wave * 8 + srow;
                gload16(Ap + (size_t)r * 1024 + k0 + swz, &As[nxt][r * 64 + ch8]);
                gload16(Bp + (size_t)r * 1024 + k0 + swz, &Bs[nxt][r * 64 + ch8]);
            }
        }
        #pragma unroll
        for (int kk = 0; kk < 2; kk++) {
            bf16x8 af[4], bfr[4];
            #pragma unroll
            for (int i = 0; i < 4; i++)
                af[i] = *(const bf16x8*)&As[cur][(wrow + i * 16 + l15) * 64 +
                                                (((kk * 4 + quad) ^ sw)) * 8];
            #pragma unroll
            for (int j = 0; j < 4; j++)
                bfr[j] = *(const bf16x8*)&Bs[cur][(wcol + j * 16 + l15) * 64 +
                                                 (((kk * 4 + quad) ^ sw)) * 8];
            #pragma unroll
            for (int i = 0; i < 4; i++)
                #pragma unroll
                for (int j = 0; j < 4; j++)
                    acc[i][j] = __builtin_amdgcn_mfma_f32_16x16x32_bf16(
                        af[i], bfr[j], acc[i][j], 0, 0, 0);
        }
    }

    // C/D layout: col=lane&15, row=quad*4+reg (m89/m91 verified)
    if (z < 2) {
        const float* bias = (z == 0) ? bq : bk;
        #pragma unroll
        for (int j = 0; j < 4; j++) {
            int col = y0 + wcol + j * 16 + l15;
            float bcol = bias[col];
            int h = col >> 6, d = col & 63;
            #pragma unroll
            for (int i = 0; i < 4; i++)
                #pragma unroll
                for (int r = 0; r < 4; r++) {
                    int row = x0 + wrow + i * 16 + quad * 4 + r;
                    int b = row >> 11, s = row & 2047;
                    float v = acc[i][j][r] + bcol;
                    if (z == 0)
                        Qb[(size_t)((b * 16 + h) * 2048 + s) * 64 + d] = f2bf(v * QSCALE);
                    else
                        Kb[(size_t)((b * 16 + h) * 2048 + s) * 64 + d] = f2bf(v);
                }
        }
    } else {
        #pragma unroll
        for (int i = 0; i < 4; i++)
            #pragma unroll
            for (int r = 0; r < 4; r++) {
                int rowd = y0 + wrow + i * 16 + quad * 4 + r;   // d_full 0..1023
                float brow = bv[rowd];
                #pragma unroll
                for (int j = 0; j < 4; j++) {
                    int colm = x0 + wcol + j * 16 + l15;        // m 0..4095
                    int b = colm >> 11, s = colm & 2047;
                    Vt[(size_t)(b * 1024 + rowd) * 2048 + s] = f2bf(acc[i][j][r] + brow);
                }
            }
    }
}

// ---------------- flash attention (fixed-max, split-T, K/V dbuf) -----------
// 128 Q rows/block, 4 waves x 32 rows (mi=2). l via MFMA ones-column.
// K/V double-buffered: loads for tile t+1 fly during compute of tile t.
__global__ __launch_bounds__(256) void attn_kernel(
    const unsigned short* __restrict__ Qb, const unsigned short* __restrict__ Kb,
    const unsigned short* __restrict__ Vt, unsigned short* __restrict__ Cc,
    float* __restrict__ Op, float* __restrict__ Lp, int tlen, int do_split) {
    const int bh = blockIdx.y;            // 0..31
    const int b = bh >> 4, h = bh & 15;
    const int q0 = blockIdx.x * 128;
    const int split = blockIdx.z;
    const int tbeg = split * tlen;

    const int tid = threadIdx.x;
    const int lane = tid & 63, wave = tid >> 6;
    const int quad = lane >> 4, l15 = lane & 15;

    __shared__ __align__(16) unsigned short Ks[2][64 * 64];
    __shared__ __align__(16) unsigned short Vs[2][64 * 64];
    __shared__ __align__(16) unsigned short Ps[4][32 * LDKP];

    const unsigned short* Qbh = Qb + (size_t)bh * 2048 * 64;
    const unsigned short* Kbh = Kb + (size_t)bh * 2048 * 64;
    const unsigned short* Vbh = Vt + (size_t)bh * 64 * 2048;

    // Q fragments in registers: A-layout m=lane&15, k=quad*8+j (m120)
    bf16x8 qa[2][2];
    #pragma unroll
    for (int mi = 0; mi < 2; mi++)
        #pragma unroll
        for (int kk = 0; kk < 2; kk++)
            qa[mi][kk] = *(const bf16x8*)&Qbh[
                (size_t)(q0 + wave * 32 + mi * 16 + l15) * 64 + kk * 32 + quad * 8];

    union { unsigned short us[8]; bf16x8 v; } ones_u;
    #pragma unroll
    for (int i = 0; i < 8; i++) ones_u.us[i] = 0x3F80;
    const bf16x8 onesv = ones_u.v;

    f32x4 o[2][4] = {};
    f32x4 ol[2] = {};

    const int srow = lane >> 3;                 // 0..7
    const int r0s = wave * 16 + srow;           // staging rows (2 per lane)
    const int ch8 = (lane & 7) * 8;
    const int swz = (((lane & 7) ^ srow)) * 8;  // row&7 == srow for both rows
    const int sw  = (l15 & 7);

    // prologue: stage tile 0 into buffer 0
    {
        const int t0 = tbeg;
        gload16(&Kbh[(size_t)(t0 + r0s) * 64 + swz],       &Ks[0][r0s * 64 + ch8]);
        gload16(&Kbh[(size_t)(t0 + r0s + 8) * 64 + swz],   &Ks[0][(r0s + 8) * 64 + ch8]);
        gload16(&Vbh[(size_t)r0s * 2048 + t0 + swz],       &Vs[0][r0s * 64 + ch8]);
        gload16(&Vbh[(size_t)(r0s + 8) * 2048 + t0 + swz], &Vs[0][(r0s + 8) * 64 + ch8]);
    }

    const int niter = tlen >> 6;
    for (int it = 0; it < niter; it++) {
        const int cur = it & 1, nxt = cur ^ 1;
        WAIT0_BARRIER();   // cur's K/V landed everywhere; prev compute done
        if (it + 1 < niter) {
            const int t0 = tbeg + (it + 1) * 64;
            gload16(&Kbh[(size_t)(t0 + r0s) * 64 + swz],       &Ks[nxt][r0s * 64 + ch8]);
            gload16(&Kbh[(size_t)(t0 + r0s + 8) * 64 + swz],   &Ks[nxt][(r0s + 8) * 64 + ch8]);
            gload16(&Vbh[(size_t)r0s * 2048 + t0 + swz],       &Vs[nxt][r0s * 64 + ch8]);
            gload16(&Vbh[(size_t)(r0s + 8) * 2048 + t0 + swz], &Vs[nxt][(r0s + 8) * 64 + ch8]);
        }

        // S = Q K^T (log2 domain), both mi share each kf read
        f32x4 sf[2][4] = {};
        #pragma unroll
        for (int j = 0; j < 4; j++)
            #pragma unroll
            for (int kk = 0; kk < 2; kk++) {
                bf16x8 kf = *(const bf16x8*)&Ks[cur][(j * 16 + l15) * 64 +
                                                     (((kk * 4 + quad) ^ sw)) * 8];
                sf[0][j] = __builtin_amdgcn_mfma_f32_16x16x32_bf16(qa[0][kk], kf, sf[0][j], 0, 0, 0);
                sf[1][j] = __builtin_amdgcn_mfma_f32_16x16x32_bf16(qa[1][kk], kf, sf[1][j], 0, 0, 0);
            }

        // P = exp2(S), truncated bf16, staged to LDS (C->A layout transform)
        #pragma unroll
        for (int mi = 0; mi < 2; mi++)
            #pragma unroll
            for (int j = 0; j < 4; j++)
                #pragma unroll
                for (int r = 0; r < 4; r++) {
                    float p = EXPFN(sf[mi][j][r]);
                    Ps[wave][(mi * 16 + quad * 4 + r) * LDKP + j * 16 + l15] =
                        (unsigned short)(__float_as_uint(p) >> 16);
                }

        asm volatile("s_waitcnt lgkmcnt(0)" ::: "memory");  // P visible wave-wide

        // O += P V ; l += P @ ones  (vf shared across mi)
        #pragma unroll
        for (int kk = 0; kk < 2; kk++) {
            bf16x8 pf0 = *(const bf16x8*)&Ps[wave][(l15) * LDKP + kk * 32 + quad * 8];
            bf16x8 pf1 = *(const bf16x8*)&Ps[wave][(16 + l15) * LDKP + kk * 32 + quad * 8];
            ol[0] = __builtin_amdgcn_mfma_f32_16x16x32_bf16(pf0, onesv, ol[0], 0, 0, 0);
            ol[1] = __builtin_amdgcn_mfma_f32_16x16x32_bf16(pf1, onesv, ol[1], 0, 0, 0);
            #pragma unroll
            for (int j = 0; j < 4; j++) {
                bf16x8 vf = *(const bf16x8*)&Vs[cur][(j * 16 + l15) * 64 +
                                                     (((kk * 4 + quad) ^ sw)) * 8];
                o[0][j] = __builtin_amdgcn_mfma_f32_16x16x32_bf16(pf0, vf, o[0][j], 0, 0, 0);
                o[1][j] = __builtin_amdgcn_mfma_f32_16x16x32_bf16(pf1, vf, o[1][j], 0, 0, 0);
            }
        }
    }

    if (do_split) {
        float* Opd = Op + (size_t)(split * 32 + bh) * 2048 * 64;
        float* Lpd = Lp + (size_t)(split * 32 + bh) * 2048;
        #pragma unroll
        for (int mi = 0; mi < 2; mi++)
            #pragma unroll
            for (int r = 0; r < 4; r++) {
                int s = q0 + wave * 32 + mi * 16 + quad * 4 + r;
                if (l15 == 0) Lpd[s] = ol[mi][r];
                #pragma unroll
                for (int j = 0; j < 4; j++)
                    Opd[(size_t)s * 64 + j * 16 + l15] = o[mi][j][r];
            }
    } else {
        #pragma unroll
        for (int mi = 0; mi < 2; mi++)
            #pragma unroll
            for (int r = 0; r < 4; r++) {
                float inv = 1.f / ol[mi][r];
                int s = q0 + wave * 32 + mi * 16 + quad * 4 + r;
                size_t row = (size_t)(b * 2048 + s);
                #pragma unroll
                for (int j = 0; j < 4; j++)
                    Cc[row * 1024 + h * 64 + j * 16 + l15] = f2bf(o[mi][j][r] * inv);
            }
    }
}

// ---------------- combine split partials -> Cc bf16 ------------------------
__global__ __launch_bounds__(256) void combine_kernel(
    const float4* __restrict__ Op, const float* __restrict__ Lp,
    unsigned short* __restrict__ Cc) {
    int idx = blockIdx.x * 256 + threadIdx.x;       // 0 .. 32*2048*16-1
    int d4 = idx & 15;
    int s = (idx >> 4) & 2047;
    int bh = idx >> 15;
    const size_t half4 = (size_t)32 * 2048 * 16;
    float4 a = Op[(size_t)idx], c = Op[half4 + (size_t)idx];
    float l = Lp[bh * 2048 + s] + Lp[32 * 2048 + bh * 2048 + s];
    float inv = 1.f / l;
    ushort4 o;
    o.x = f2bf((a.x + c.x) * inv); o.y = f2bf((a.y + c.y) * inv);
    o.z = f2bf((a.z + c.z) * inv); o.w = f2bf((a.w + c.w) * inv);
    int b = bh >> 4, h = bh & 15;
    *(ushort4*)&Cc[((size_t)(b * 2048 + s)) * 1024 + h * 64 + d4 * 4] = o;
}

// ---------------- output projection (128x128 tile, dbuf): Cc Wo^T + bo -----
__global__ __launch_bounds__(256) void gemm_out_kernel(
    const unsigned short* __restrict__ Cc, const unsigned short* __restrict__ Wot,
    const float* __restrict__ bo, float* __restrict__ out) {
    const int m0 = blockIdx.x * 128;   // over 4096
    const int n0 = blockIdx.y * 128;   // over 1024

    __shared__ __align__(16) unsigned short As[2][128 * 64];
    __shared__ __align__(16) unsigned short Bs[2][128 * 64];

    const int tid = threadIdx.x;
    const int lane = tid & 63, wave = tid >> 6;
    const int quad = lane >> 4, l15 = lane & 15;
    const int wrow = (wave >> 1) * 64, wcol = (wave & 1) * 64;

    f32x4 acc[4][4] = {};
    const int srow = lane >> 3;
    const int ch8 = (lane & 7) * 8;
    const int swz = (((lane & 7) ^ srow)) * 8;
    const int sw  = (l15 & 7);

    #pragma unroll
    for (int c = 0; c < 4; c++) {
        int r = c * 32 + wave * 8 + srow;
        gload16(Cc + (size_t)(m0 + r) * 1024 + swz,  &As[0][r * 64 + ch8]);
        gload16(Wot + (size_t)(n0 + r) * 1024 + swz, &Bs[0][r * 64 + ch8]);
    }

    for (int k = 0; k < 16; k++) {
        const int cur = k & 1, nxt = cur ^ 1;
        WAIT0_BARRIER();
        if (k < 15) {
            int k0 = (k + 1) * 64;
            #pragma unroll
            for (int c = 0; c < 4; c++) {
                int r = c * 32 + wave * 8 + srow;
                gload16(Cc + (size_t)(m0 + r) * 1024 + k0 + swz,  &As[nxt][r * 64 + ch8]);
                gload16(Wot + (size_t)(n0 + r) * 1024 + k0 + swz, &Bs[nxt][r * 64 + ch8]);
            }
        }
        #pragma unroll
        for (int kk = 0; kk < 2; kk++) {
            bf16x8 af[4], bfr[4];
            #pragma unroll
            for (int i = 0; i < 4; i++)
                af[i] = *(const bf16x8*)&As[cur][(wrow + i * 16 + l15) * 64 +
                                                (((kk * 4 + quad) ^ sw)) * 8];
            #pragma unroll
            for (int j = 0; j < 4; j++)
                bfr[j] = *(const bf16x8*)&Bs[cur][(wcol + j * 16 + l15) * 64 +
                                                 (((kk * 4 + quad) ^ sw)) * 8];
            #pragma unroll
            for (int i = 0; i < 4; i++)
                #pragma unroll
                for (int j = 0; j < 4; j++)
                    acc[i][j] = __builtin_amdgcn_mfma_f32_16x16x32_bf16(
                        af[i], bfr[j], acc[i][j], 0, 0, 0);
        }
    }

    #pragma unroll
    for (int j = 0; j < 4; j++) {
        int col = n0 + wcol + j * 16 + l15;
        float bcol = bo[col];
        #pragma unroll
        for (int i = 0; i < 4; i++)
            #pragma unroll
            for (int r = 0; r < 4; r++) {
                int row = m0 + wrow + i * 16 + quad * 4 + r;
                out[(size_t)row * 1024 + col] = acc[i][j][r] + bcol;
            }
    }
}

// ---------------------------------------------------------------------------
extern "C" void kernel_launch(void* const* d_in, const int* in_sizes, int n_in,
                              void* d_out, int out_size, void* d_ws, size_t ws_size,
                              hipStream_t stream) {
    const float* X  = (const float*)d_in[0];
    const float* Wq = (const float*)d_in[1];
    const float* bq = (const float*)d_in[2];
    const float* Wk = (const float*)d_in[3];
    const float* bk = (const float*)d_in[4];
    const float* Wv = (const float*)d_in[5];
    const float* bv = (const float*)d_in[6];
    const float* Wo = (const float*)d_in[7];
    const float* bo = (const float*)d_in[8];
    float* out = (float*)d_out;

    char* ws = (char*)d_ws;
    unsigned short* Xb = (unsigned short*)(ws);                    //  8 MB
    unsigned short* Wt = (unsigned short*)(ws + (8u  << 20));      //  8 MB (4 mats)
    unsigned short* Qb = (unsigned short*)(ws + (16u << 20));      //  8 MB
    unsigned short* Kb = (unsigned short*)(ws + (24u << 20));      //  8 MB
    unsigned short* Vt = (unsigned short*)(ws + (32u << 20));      //  8 MB
    unsigned short* Cc = (unsigned short*)(ws + (40u << 20));      //  8 MB
    float* Op = (float*)(ws + (48u << 20));                        // 32 MB
    float* Lp = (float*)(ws + (48u << 20) + 33554432u);            // 512 KB
    const bool use_split = ws_size >= ((size_t)(48u << 20) + 33554432u + 524288u);

    prep_kernel<<<dim3(32, 32, 5), 256, 0, stream>>>(X, (ushort4*)Xb, Wq, Wk, Wv, Wo, Wt);
    gemm_qkv_kernel<<<dim3(32, 8, 3), 256, 0, stream>>>(Xb, Wt, bq, bk, bv, Qb, Kb, Vt);
    if (use_split) {
        attn_kernel<<<dim3(16, 32, 2), 256, 0, stream>>>(Qb, Kb, Vt, Cc, Op, Lp, 1024, 1);
        combine_kernel<<<4096, 256, 0, stream>>>((const float4*)Op, Lp, Cc);
    } else {
        attn_kernel<<<dim3(16, 32, 1), 256, 0, stream>>>(Qb, Kb, Vt, Cc, Op, Lp, 2048, 0);
    }
    gemm_out_kernel<<<dim3(32, 8), 256, 0, stream>>>(Cc, Wt + 3u * 1024 * 1024, bo, out);
}

// Round 8
// 208.264 us; speedup vs baseline: 1.0843x; 1.0454x over previous
//
#include <hip/hip_runtime.h>

// ---------------------------------------------------------------------------
// MultiHeadSelfAttention: B=2, S=2048, D=1024, H=16, HD=64, fp32 in/out.
// prep (cast X + transpose W) -> fused QKV bf16 MFMA GEMM (m97 structure:
// single-buffer BK=64, 32 KB LDS, 3 blocks/CU) -> split-T flash attention
// (fixed-max softmax, 128-row Q blocks, K/V dbuf) -> combine -> out
// projection GEMM (128x64 single-buffer, 512 blocks = 2/CU).
// All matmuls: mfma_f32_16x16x32_bf16, fp32 accum.
// XOR swizzle: LDS rows are 64 shorts (128 B); chunk c (16 B) of row r holds
// global chunk c^(r&7). Staging permutes the GLOBAL address (global_load_lds
// dest must be base+lane*16); fragment reads apply the same permutation.
// ---------------------------------------------------------------------------

typedef __bf16 bf16x8 __attribute__((ext_vector_type(8)));
typedef float  f32x4  __attribute__((ext_vector_type(4)));

#if __has_builtin(__builtin_amdgcn_exp2f)
#define EXPFN(x) __builtin_amdgcn_exp2f(x)
#define QSCALE (0.125f * 1.44269504088896f)   // fold log2(e) into Q
#else
#define EXPFN(x) __expf(x)
#define QSCALE 0.125f
#endif

#define LDKP 74  // Ps leading dim (shorts): odd dword stride breaks collisions

__device__ __forceinline__ unsigned short f2bf(float f) {
    unsigned int u = __float_as_uint(f);
    u += 0x7FFFu + ((u >> 16) & 1u);   // RNE; finite inputs
    return (unsigned short)(u >> 16);
}

// async global->LDS, 16B per lane; HW dest = firstlane(lptr) + lane*16.
__device__ __forceinline__ void gload16(const void* g, void* l) {
    __builtin_amdgcn_global_load_lds(
        (const __attribute__((address_space(1))) void*)g,
        (__attribute__((address_space(3))) void*)l, 16, 0, 0);
}

#define WAIT0_BARRIER() asm volatile("s_waitcnt vmcnt(0)\n\ts_barrier" ::: "memory")

// ---------------- prep: cast X (z=4) + transpose/cast W (z=0..3) -----------
__global__ __launch_bounds__(256) void prep_kernel(
    const float* __restrict__ X, ushort4* __restrict__ Xb,
    const float* __restrict__ Wq, const float* __restrict__ Wk,
    const float* __restrict__ Wv, const float* __restrict__ Wo,
    unsigned short* __restrict__ Wt_all) {
    const int z = blockIdx.z;
    if (z == 4) {
        int base = (blockIdx.y * 32 + blockIdx.x) * 1024 + threadIdx.x;
        const float4* X4 = (const float4*)X;
        #pragma unroll
        for (int c = 0; c < 4; c++) {
            int i = base + c * 256;
            float4 v = X4[i];
            ushort4 o;
            o.x = f2bf(v.x); o.y = f2bf(v.y); o.z = f2bf(v.z); o.w = f2bf(v.w);
            Xb[i] = o;
        }
        return;
    }
    __shared__ float tile[32][33];
    const float* W = (z == 0) ? Wq : (z == 1) ? Wk : (z == 2) ? Wv : Wo;
    unsigned short* Wt = Wt_all + (size_t)z * 1024 * 1024;
    int c0 = blockIdx.x * 32, r0 = blockIdx.y * 32;
    int x = threadIdx.x & 31, y = threadIdx.x >> 5;   // (32, 8)
    for (int j = 0; j < 32; j += 8)
        tile[y + j][x] = W[(r0 + y + j) * 1024 + c0 + x];
    __syncthreads();
    for (int j = 0; j < 32; j += 8)
        Wt[(c0 + y + j) * 1024 + r0 + x] = f2bf(tile[x][y + j]);
}

// ---------------- fused QKV GEMM (128x128 tile, BK=64, single-buffer) ------
// m97 structure: stage -> vmcnt(0)+barrier -> compute -> barrier. 32 KB LDS,
// grid 768 = 3 blocks/CU co-resident (implicit cross-block overlap, m114).
// z=0: Q = X Wq^T + bq, scaled -> Qb[B,H,S,64]
// z=1: K = X Wk^T + bk        -> Kb[B,H,S,64]
// z=2: V^T = Wv^T X^T (+bv)   -> Vt[B,H,64,S]   (A/B roles swapped)
__global__ __launch_bounds__(256) void gemm_qkv_kernel(
    const unsigned short* __restrict__ Xb, const unsigned short* __restrict__ Wt_all,
    const float* __restrict__ bq, const float* __restrict__ bk,
    const float* __restrict__ bv,
    unsigned short* __restrict__ Qb, unsigned short* __restrict__ Kb,
    unsigned short* __restrict__ Vt) {
    const int z = blockIdx.z;
    const int x0 = blockIdx.x * 128;   // over 4096 (X rows)
    const int y0 = blockIdx.y * 128;   // over 1024 (W rows)

    const unsigned short* Ap;
    const unsigned short* Bp;
    if (z < 2) {
        Ap = Xb + (size_t)x0 * 1024;
        Bp = Wt_all + (size_t)z * 1024 * 1024 + (size_t)y0 * 1024;
    } else {
        Ap = Wt_all + (size_t)2 * 1024 * 1024 + (size_t)y0 * 1024;
        Bp = Xb + (size_t)x0 * 1024;
    }

    __shared__ __align__(16) unsigned short As[128 * 64];
    __shared__ __align__(16) unsigned short Bs[128 * 64];

    const int tid = threadIdx.x;
    const int lane = tid & 63, wave = tid >> 6;
    const int quad = lane >> 4, l15 = lane & 15;
    const int wrow = (wave >> 1) * 64, wcol = (wave & 1) * 64;

    f32x4 acc[4][4] = {};

    const int srow = lane >> 3;            // 0..7
    const int ch8  = (lane & 7) * 8;       // natural chunk offset (shorts)
    const int swz  = (((lane & 7) ^ srow)) * 8;  // swizzled source chunk
    const int sw   = (l15 & 7);            // read-side row swizzle key

    for (int k0 = 0; k0 < 1024; k0 += 64) {
        #pragma unroll
        for (int c = 0; c < 4; c++) {
            int r = c * 32 + wave * 8 + srow;
            gload16(Ap + (size_t)r * 1024 + k0 + swz, &As[r * 64 + ch8]);
            gload16(Bp + (size_t)r * 1024 + k0 + swz, &Bs[r * 64 + ch8]);
        }
        WAIT0_BARRIER();
        #pragma unroll
        for (int kk = 0; kk < 2; kk++) {
            bf16x8 af[4], bfr[4];
            #pragma unroll
            for (int i = 0; i < 4; i++)
                af[i] = *(const bf16x8*)&As[(wrow + i * 16 + l15) * 64 +
                                            (((kk * 4 + quad) ^ sw)) * 8];
            #pragma unroll
            for (int j = 0; j < 4; j++)
                bfr[j] = *(const bf16x8*)&Bs[(wcol + j * 16 + l15) * 64 +
                                             (((kk * 4 + quad) ^ sw)) * 8];
            #pragma unroll
            for (int i = 0; i < 4; i++)
                #pragma unroll
                for (int j = 0; j < 4; j++)
                    acc[i][j] = __builtin_amdgcn_mfma_f32_16x16x32_bf16(
                        af[i], bfr[j], acc[i][j], 0, 0, 0);
        }
        __syncthreads();
    }

    // C/D layout: col=lane&15, row=quad*4+reg (m89/m91 verified)
    if (z < 2) {
        const float* bias = (z == 0) ? bq : bk;
        #pragma unroll
        for (int j = 0; j < 4; j++) {
            int col = y0 + wcol + j * 16 + l15;
            float bcol = bias[col];
            int h = col >> 6, d = col & 63;
            #pragma unroll
            for (int i = 0; i < 4; i++)
                #pragma unroll
                for (int r = 0; r < 4; r++) {
                    int row = x0 + wrow + i * 16 + quad * 4 + r;
                    int b = row >> 11, s = row & 2047;
                    float v = acc[i][j][r] + bcol;
                    if (z == 0)
                        Qb[(size_t)((b * 16 + h) * 2048 + s) * 64 + d] = f2bf(v * QSCALE);
                    else
                        Kb[(size_t)((b * 16 + h) * 2048 + s) * 64 + d] = f2bf(v);
                }
        }
    } else {
        #pragma unroll
        for (int i = 0; i < 4; i++)
            #pragma unroll
            for (int r = 0; r < 4; r++) {
                int rowd = y0 + wrow + i * 16 + quad * 4 + r;   // d_full 0..1023
                float brow = bv[rowd];
                #pragma unroll
                for (int j = 0; j < 4; j++) {
                    int colm = x0 + wcol + j * 16 + l15;        // m 0..4095
                    int b = colm >> 11, s = colm & 2047;
                    Vt[(size_t)(b * 1024 + rowd) * 2048 + s] = f2bf(acc[i][j][r] + brow);
                }
            }
    }
}

// ---------------- flash attention (fixed-max, split-T, K/V dbuf) -----------
// 128 Q rows/block, 4 waves x 32 rows (mi=2). l via MFMA ones-column.
__global__ __launch_bounds__(256) void attn_kernel(
    const unsigned short* __restrict__ Qb, const unsigned short* __restrict__ Kb,
    const unsigned short* __restrict__ Vt, unsigned short* __restrict__ Cc,
    float* __restrict__ Op, float* __restrict__ Lp, int tlen, int do_split) {
    const int bh = blockIdx.y;            // 0..31
    const int b = bh >> 4, h = bh & 15;
    const int q0 = blockIdx.x * 128;
    const int split = blockIdx.z;
    const int tbeg = split * tlen;

    const int tid = threadIdx.x;
    const int lane = tid & 63, wave = tid >> 6;
    const int quad = lane >> 4, l15 = lane & 15;

    __shared__ __align__(16) unsigned short Ks[2][64 * 64];
    __shared__ __align__(16) unsigned short Vs[2][64 * 64];
    __shared__ __align__(16) unsigned short Ps[4][32 * LDKP];

    const unsigned short* Qbh = Qb + (size_t)bh * 2048 * 64;
    const unsigned short* Kbh = Kb + (size_t)bh * 2048 * 64;
    const unsigned short* Vbh = Vt + (size_t)bh * 64 * 2048;

    // Q fragments in registers: A-layout m=lane&15, k=quad*8+j (m120)
    bf16x8 qa[2][2];
    #pragma unroll
    for (int mi = 0; mi < 2; mi++)
        #pragma unroll
        for (int kk = 0; kk < 2; kk++)
            qa[mi][kk] = *(const bf16x8*)&Qbh[
                (size_t)(q0 + wave * 32 + mi * 16 + l15) * 64 + kk * 32 + quad * 8];

    union { unsigned short us[8]; bf16x8 v; } ones_u;
    #pragma unroll
    for (int i = 0; i < 8; i++) ones_u.us[i] = 0x3F80;
    const bf16x8 onesv = ones_u.v;

    f32x4 o[2][4] = {};
    f32x4 ol[2] = {};

    const int srow = lane >> 3;                 // 0..7
    const int r0s = wave * 16 + srow;           // staging rows (2 per lane)
    const int ch8 = (lane & 7) * 8;
    const int swz = (((lane & 7) ^ srow)) * 8;  // row&7 == srow for both rows
    const int sw  = (l15 & 7);

    // prologue: stage tile 0 into buffer 0
    {
        const int t0 = tbeg;
        gload16(&Kbh[(size_t)(t0 + r0s) * 64 + swz],       &Ks[0][r0s * 64 + ch8]);
        gload16(&Kbh[(size_t)(t0 + r0s + 8) * 64 + swz],   &Ks[0][(r0s + 8) * 64 + ch8]);
        gload16(&Vbh[(size_t)r0s * 2048 + t0 + swz],       &Vs[0][r0s * 64 + ch8]);
        gload16(&Vbh[(size_t)(r0s + 8) * 2048 + t0 + swz], &Vs[0][(r0s + 8) * 64 + ch8]);
    }

    const int niter = tlen >> 6;
    for (int it = 0; it < niter; it++) {
        const int cur = it & 1, nxt = cur ^ 1;
        WAIT0_BARRIER();   // cur's K/V landed everywhere; prev compute done
        if (it + 1 < niter) {
            const int t0 = tbeg + (it + 1) * 64;
            gload16(&Kbh[(size_t)(t0 + r0s) * 64 + swz],       &Ks[nxt][r0s * 64 + ch8]);
            gload16(&Kbh[(size_t)(t0 + r0s + 8) * 64 + swz],   &Ks[nxt][(r0s + 8) * 64 + ch8]);
            gload16(&Vbh[(size_t)r0s * 2048 + t0 + swz],       &Vs[nxt][r0s * 64 + ch8]);
            gload16(&Vbh[(size_t)(r0s + 8) * 2048 + t0 + swz], &Vs[nxt][(r0s + 8) * 64 + ch8]);
        }

        // S = Q K^T (log2 domain), both mi share each kf read
        f32x4 sf[2][4] = {};
        #pragma unroll
        for (int j = 0; j < 4; j++)
            #pragma unroll
            for (int kk = 0; kk < 2; kk++) {
                bf16x8 kf = *(const bf16x8*)&Ks[cur][(j * 16 + l15) * 64 +
                                                     (((kk * 4 + quad) ^ sw)) * 8];
                sf[0][j] = __builtin_amdgcn_mfma_f32_16x16x32_bf16(qa[0][kk], kf, sf[0][j], 0, 0, 0);
                sf[1][j] = __builtin_amdgcn_mfma_f32_16x16x32_bf16(qa[1][kk], kf, sf[1][j], 0, 0, 0);
            }

        // P = exp2(S), truncated bf16, staged to LDS (C->A layout transform)
        #pragma unroll
        for (int mi = 0; mi < 2; mi++)
            #pragma unroll
            for (int j = 0; j < 4; j++)
                #pragma unroll
                for (int r = 0; r < 4; r++) {
                    float p = EXPFN(sf[mi][j][r]);
                    Ps[wave][(mi * 16 + quad * 4 + r) * LDKP + j * 16 + l15] =
                        (unsigned short)(__float_as_uint(p) >> 16);
                }

        asm volatile("s_waitcnt lgkmcnt(0)" ::: "memory");  // P visible wave-wide

        // O += P V ; l += P @ ones  (vf shared across mi)
        #pragma unroll
        for (int kk = 0; kk < 2; kk++) {
            bf16x8 pf0 = *(const bf16x8*)&Ps[wave][(l15) * LDKP + kk * 32 + quad * 8];
            bf16x8 pf1 = *(const bf16x8*)&Ps[wave][(16 + l15) * LDKP + kk * 32 + quad * 8];
            ol[0] = __builtin_amdgcn_mfma_f32_16x16x32_bf16(pf0, onesv, ol[0], 0, 0, 0);
            ol[1] = __builtin_amdgcn_mfma_f32_16x16x32_bf16(pf1, onesv, ol[1], 0, 0, 0);
            #pragma unroll
            for (int j = 0; j < 4; j++) {
                bf16x8 vf = *(const bf16x8*)&Vs[cur][(j * 16 + l15) * 64 +
                                                     (((kk * 4 + quad) ^ sw)) * 8];
                o[0][j] = __builtin_amdgcn_mfma_f32_16x16x32_bf16(pf0, vf, o[0][j], 0, 0, 0);
                o[1][j] = __builtin_amdgcn_mfma_f32_16x16x32_bf16(pf1, vf, o[1][j], 0, 0, 0);
            }
        }
    }

    if (do_split) {
        float* Opd = Op + (size_t)(split * 32 + bh) * 2048 * 64;
        float* Lpd = Lp + (size_t)(split * 32 + bh) * 2048;
        #pragma unroll
        for (int mi = 0; mi < 2; mi++)
            #pragma unroll
            for (int r = 0; r < 4; r++) {
                int s = q0 + wave * 32 + mi * 16 + quad * 4 + r;
                if (l15 == 0) Lpd[s] = ol[mi][r];
                #pragma unroll
                for (int j = 0; j < 4; j++)
                    Opd[(size_t)s * 64 + j * 16 + l15] = o[mi][j][r];
            }
    } else {
        #pragma unroll
        for (int mi = 0; mi < 2; mi++)
            #pragma unroll
            for (int r = 0; r < 4; r++) {
                float inv = 1.f / ol[mi][r];
                int s = q0 + wave * 32 + mi * 16 + quad * 4 + r;
                size_t row = (size_t)(b * 2048 + s);
                #pragma unroll
                for (int j = 0; j < 4; j++)
                    Cc[row * 1024 + h * 64 + j * 16 + l15] = f2bf(o[mi][j][r] * inv);
            }
    }
}

// ---------------- combine split partials -> Cc bf16 ------------------------
__global__ __launch_bounds__(256) void combine_kernel(
    const float4* __restrict__ Op, const float* __restrict__ Lp,
    unsigned short* __restrict__ Cc) {
    int idx = blockIdx.x * 256 + threadIdx.x;       // 0 .. 32*2048*16-1
    int d4 = idx & 15;
    int s = (idx >> 4) & 2047;
    int bh = idx >> 15;
    const size_t half4 = (size_t)32 * 2048 * 16;
    float4 a = Op[(size_t)idx], c = Op[half4 + (size_t)idx];
    float l = Lp[bh * 2048 + s] + Lp[32 * 2048 + bh * 2048 + s];
    float inv = 1.f / l;
    ushort4 o;
    o.x = f2bf((a.x + c.x) * inv); o.y = f2bf((a.y + c.y) * inv);
    o.z = f2bf((a.z + c.z) * inv); o.w = f2bf((a.w + c.w) * inv);
    int b = bh >> 4, h = bh & 15;
    *(ushort4*)&Cc[((size_t)(b * 2048 + s)) * 1024 + h * 64 + d4 * 4] = o;
}

// ---------------- output projection (128x64 tile, single-buffer) -----------
// grid (32,16) = 512 blocks = 2/CU; LDS 24 KB; wave tile 64x32.
__global__ __launch_bounds__(256) void gemm_out_kernel(
    const unsigned short* __restrict__ Cc, const unsigned short* __restrict__ Wot,
    const float* __restrict__ bo, float* __restrict__ out) {
    const int m0 = blockIdx.x * 128;   // over 4096
    const int n0 = blockIdx.y * 64;    // over 1024

    __shared__ __align__(16) unsigned short As[128 * 64];
    __shared__ __align__(16) unsigned short Bs[64 * 64];

    const int tid = threadIdx.x;
    const int lane = tid & 63, wave = tid >> 6;
    const int quad = lane >> 4, l15 = lane & 15;
    const int wrow = (wave >> 1) * 64, wcol = (wave & 1) * 32;

    f32x4 acc[4][2] = {};
    const int srow = lane >> 3;
    const int ch8 = (lane & 7) * 8;
    const int swz = (((lane & 7) ^ srow)) * 8;
    const int sw  = (l15 & 7);

    for (int k0 = 0; k0 < 1024; k0 += 64) {
        #pragma unroll
        for (int c = 0; c < 4; c++) {
            int r = c * 32 + wave * 8 + srow;
            gload16(Cc + (size_t)(m0 + r) * 1024 + k0 + swz, &As[r * 64 + ch8]);
            if (c < 2)
                gload16(Wot + (size_t)(n0 + r) * 1024 + k0 + swz, &Bs[r * 64 + ch8]);
        }
        WAIT0_BARRIER();
        #pragma unroll
        for (int kk = 0; kk < 2; kk++) {
            bf16x8 af[4], bfr[2];
            #pragma unroll
            for (int i = 0; i < 4; i++)
                af[i] = *(const bf16x8*)&As[(wrow + i * 16 + l15) * 64 +
                                            (((kk * 4 + quad) ^ sw)) * 8];
            #pragma unroll
            for (int j = 0; j < 2; j++)
                bfr[j] = *(const bf16x8*)&Bs[(wcol + j * 16 + l15) * 64 +
                                             (((kk * 4 + quad) ^ sw)) * 8];
            #pragma unroll
            for (int i = 0; i < 4; i++)
                #pragma unroll
                for (int j = 0; j < 2; j++)
                    acc[i][j] = __builtin_amdgcn_mfma_f32_16x16x32_bf16(
                        af[i], bfr[j], acc[i][j], 0, 0, 0);
        }
        __syncthreads();
    }

    #pragma unroll
    for (int j = 0; j < 2; j++) {
        int col = n0 + wcol + j * 16 + l15;
        float bcol = bo[col];
        #pragma unroll
        for (int i = 0; i < 4; i++)
            #pragma unroll
            for (int r = 0; r < 4; r++) {
                int row = m0 + wrow + i * 16 + quad * 4 + r;
                out[(size_t)row * 1024 + col] = acc[i][j][r] + bcol;
            }
    }
}

// ---------------------------------------------------------------------------
extern "C" void kernel_launch(void* const* d_in, const int* in_sizes, int n_in,
                              void* d_out, int out_size, void* d_ws, size_t ws_size,
                              hipStream_t stream) {
    const float* X  = (const float*)d_in[0];
    const float* Wq = (const float*)d_in[1];
    const float* bq = (const float*)d_in[2];
    const float* Wk = (const float*)d_in[3];
    const float* bk = (const float*)d_in[4];
    const float* Wv = (const float*)d_in[5];
    const float* bv = (const float*)d_in[6];
    const float* Wo = (const float*)d_in[7];
    const float* bo = (const float*)d_in[8];
    float* out = (float*)d_out;

    char* ws = (char*)d_ws;
    unsigned short* Xb = (unsigned short*)(ws);                    //  8 MB
    unsigned short* Wt = (unsigned short*)(ws + (8u  << 20));      //  8 MB (4 mats)
    unsigned short* Qb = (unsigned short*)(ws + (16u << 20));      //  8 MB
    unsigned short* Kb = (unsigned short*)(ws + (24u << 20));      //  8 MB
    unsigned short* Vt = (unsigned short*)(ws + (32u << 20));      //  8 MB
    unsigned short* Cc = (unsigned short*)(ws + (40u << 20));      //  8 MB
    float* Op = (float*)(ws + (48u << 20));                        // 32 MB
    float* Lp = (float*)(ws + (48u << 20) + 33554432u);            // 512 KB
    const bool use_split = ws_size >= ((size_t)(48u << 20) + 33554432u + 524288u);

    prep_kernel<<<dim3(32, 32, 5), 256, 0, stream>>>(X, (ushort4*)Xb, Wq, Wk, Wv, Wo, Wt);
    gemm_qkv_kernel<<<dim3(32, 8, 3), 256, 0, stream>>>(Xb, Wt, bq, bk, bv, Qb, Kb, Vt);
    if (use_split) {
        attn_kernel<<<dim3(16, 32, 2), 256, 0, stream>>>(Qb, Kb, Vt, Cc, Op, Lp, 1024, 1);
        combine_kernel<<<4096, 256, 0, stream>>>((const float4*)Op, Lp, Cc);
    } else {
        attn_kernel<<<dim3(16, 32, 1), 256, 0, stream>>>(Qb, Kb, Vt, Cc, Op, Lp, 2048, 0);
    }
    gemm_out_kernel<<<dim3(32, 16), 256, 0, stream>>>(Cc, Wt + 3u * 1024 * 1024, bo, out);
}

// Round 9
// 194.958 us; speedup vs baseline: 1.1583x; 1.0683x over previous
//
#include <hip/hip_runtime.h>

// ---------------------------------------------------------------------------
// MultiHeadSelfAttention: B=2, S=2048, D=1024, H=16, HD=64, fp32 in/out.
// prep (cast X + transpose W) -> QKV GEMM (z=0: Q&K fused sharing A-stage,
// 64 MFMA/iter; z=1: V^T; m97 single-buffer BK=64) -> split-T flash attention
// (fixed-max softmax, 128-row Q blocks, sync K/V staging) -> combine -> out
// projection GEMM (128x64 single-buffer). mfma_f32_16x16x32_bf16, fp32 accum.
// XOR swizzle: LDS rows are 64 shorts (128 B); chunk c (16 B) of row r holds
// global chunk c^(r&7). Staging permutes the GLOBAL address (global_load_lds
// dest must be base+lane*16); fragment reads apply the same permutation.
// ---------------------------------------------------------------------------

typedef __bf16 bf16x8 __attribute__((ext_vector_type(8)));
typedef float  f32x4  __attribute__((ext_vector_type(4)));

#if __has_builtin(__builtin_amdgcn_exp2f)
#define EXPFN(x) __builtin_amdgcn_exp2f(x)
#define QSCALE (0.125f * 1.44269504088896f)   // fold log2(e) into Q
#else
#define EXPFN(x) __expf(x)
#define QSCALE 0.125f
#endif

#define LDKP 74  // Ps leading dim (shorts): odd dword stride breaks collisions

__device__ __forceinline__ unsigned short f2bf(float f) {
    unsigned int u = __float_as_uint(f);
    u += 0x7FFFu + ((u >> 16) & 1u);   // RNE; finite inputs
    return (unsigned short)(u >> 16);
}

// async global->LDS, 16B per lane; HW dest = firstlane(lptr) + lane*16.
__device__ __forceinline__ void gload16(const void* g, void* l) {
    __builtin_amdgcn_global_load_lds(
        (const __attribute__((address_space(1))) void*)g,
        (__attribute__((address_space(3))) void*)l, 16, 0, 0);
}

#define WAIT0_BARRIER() asm volatile("s_waitcnt vmcnt(0)\n\ts_barrier" ::: "memory")

// ---------------- prep: cast X (z=4) + transpose/cast W (z=0..3) -----------
__global__ __launch_bounds__(256) void prep_kernel(
    const float* __restrict__ X, ushort4* __restrict__ Xb,
    const float* __restrict__ Wq, const float* __restrict__ Wk,
    const float* __restrict__ Wv, const float* __restrict__ Wo,
    unsigned short* __restrict__ Wt_all) {
    const int z = blockIdx.z;
    if (z == 4) {
        int base = (blockIdx.y * 32 + blockIdx.x) * 1024 + threadIdx.x;
        const float4* X4 = (const float4*)X;
        #pragma unroll
        for (int c = 0; c < 4; c++) {
            int i = base + c * 256;
            float4 v = X4[i];
            ushort4 o;
            o.x = f2bf(v.x); o.y = f2bf(v.y); o.z = f2bf(v.z); o.w = f2bf(v.w);
            Xb[i] = o;
        }
        return;
    }
    __shared__ float tile[32][33];
    const float* W = (z == 0) ? Wq : (z == 1) ? Wk : (z == 2) ? Wv : Wo;
    unsigned short* Wt = Wt_all + (size_t)z * 1024 * 1024;
    int c0 = blockIdx.x * 32, r0 = blockIdx.y * 32;
    int x = threadIdx.x & 31, y = threadIdx.x >> 5;   // (32, 8)
    for (int j = 0; j < 32; j += 8)
        tile[y + j][x] = W[(r0 + y + j) * 1024 + c0 + x];
    __syncthreads();
    for (int j = 0; j < 32; j += 8)
        Wt[(c0 + y + j) * 1024 + r0 + x] = f2bf(tile[x][y + j]);
}

// ---------------- QKV GEMM ------------------------------------------------
// z=0: Q&K fused — As (X rows) staged once, Bq/Bk both resident; 64 MFMA/iter.
//      Q = X Wq^T + bq (scaled) -> Qb[B,H,S,64];  K = X Wk^T + bk -> Kb.
// z=1: V^T = Wv^T X^T (+bv) -> Vt[B,H,64,S]  (A/B roles swapped).
// Grid (32,8,2) = 512 blocks = 2/CU.
__global__ __launch_bounds__(256, 2) void gemm_qkv_kernel(
    const unsigned short* __restrict__ Xb, const unsigned short* __restrict__ Wt_all,
    const float* __restrict__ bq, const float* __restrict__ bk,
    const float* __restrict__ bv,
    unsigned short* __restrict__ Qb, unsigned short* __restrict__ Kb,
    unsigned short* __restrict__ Vt) {
    const int z = blockIdx.z;
    const int x0 = blockIdx.x * 128;   // over 4096 (X rows)
    const int y0 = blockIdx.y * 128;   // over 1024 (W rows)

    __shared__ __align__(16) unsigned short As[128 * 64];
    __shared__ __align__(16) unsigned short Bs0[128 * 64];
    __shared__ __align__(16) unsigned short Bs1[128 * 64];

    const int tid = threadIdx.x;
    const int lane = tid & 63, wave = tid >> 6;
    const int quad = lane >> 4, l15 = lane & 15;
    const int wrow = (wave >> 1) * 64, wcol = (wave & 1) * 64;

    const int srow = lane >> 3;            // 0..7
    const int ch8  = (lane & 7) * 8;       // natural chunk offset (shorts)
    const int swz  = (((lane & 7) ^ srow)) * 8;  // swizzled source chunk
    const int sw   = (l15 & 7);            // read-side row swizzle key

    if (z == 0) {
        const unsigned short* Ap = Xb + (size_t)x0 * 1024;
        const unsigned short* Bq = Wt_all + (size_t)y0 * 1024;
        const unsigned short* Bk = Wt_all + (size_t)1024 * 1024 + (size_t)y0 * 1024;

        f32x4 aq[4][4] = {};
        f32x4 ak[4][4] = {};

        for (int k0 = 0; k0 < 1024; k0 += 64) {
            #pragma unroll
            for (int c = 0; c < 4; c++) {
                int r = c * 32 + wave * 8 + srow;
                gload16(Ap + (size_t)r * 1024 + k0 + swz, &As[r * 64 + ch8]);
                gload16(Bq + (size_t)r * 1024 + k0 + swz, &Bs0[r * 64 + ch8]);
                gload16(Bk + (size_t)r * 1024 + k0 + swz, &Bs1[r * 64 + ch8]);
            }
            WAIT0_BARRIER();
            #pragma unroll
            for (int kk = 0; kk < 2; kk++) {
                bf16x8 af[4], bqf[4], bkf[4];
                #pragma unroll
                for (int i = 0; i < 4; i++)
                    af[i] = *(const bf16x8*)&As[(wrow + i * 16 + l15) * 64 +
                                                (((kk * 4 + quad) ^ sw)) * 8];
                #pragma unroll
                for (int j = 0; j < 4; j++) {
                    bqf[j] = *(const bf16x8*)&Bs0[(wcol + j * 16 + l15) * 64 +
                                                  (((kk * 4 + quad) ^ sw)) * 8];
                    bkf[j] = *(const bf16x8*)&Bs1[(wcol + j * 16 + l15) * 64 +
                                                  (((kk * 4 + quad) ^ sw)) * 8];
                }
                #pragma unroll
                for (int i = 0; i < 4; i++)
                    #pragma unroll
                    for (int j = 0; j < 4; j++) {
                        aq[i][j] = __builtin_amdgcn_mfma_f32_16x16x32_bf16(
                            af[i], bqf[j], aq[i][j], 0, 0, 0);
                        ak[i][j] = __builtin_amdgcn_mfma_f32_16x16x32_bf16(
                            af[i], bkf[j], ak[i][j], 0, 0, 0);
                    }
            }
            __syncthreads();
        }

        // C/D layout: col=lane&15, row=quad*4+reg (m89/m91 verified)
        #pragma unroll
        for (int j = 0; j < 4; j++) {
            int col = y0 + wcol + j * 16 + l15;
            float bqc = bq[col], bkc = bk[col];
            int h = col >> 6, d = col & 63;
            #pragma unroll
            for (int i = 0; i < 4; i++)
                #pragma unroll
                for (int r = 0; r < 4; r++) {
                    int row = x0 + wrow + i * 16 + quad * 4 + r;
                    int b = row >> 11, s = row & 2047;
                    size_t idx = (size_t)((b * 16 + h) * 2048 + s) * 64 + d;
                    Qb[idx] = f2bf((aq[i][j][r] + bqc) * QSCALE);
                    Kb[idx] = f2bf(ak[i][j][r] + bkc);
                }
        }
    } else {
        const unsigned short* Ap = Wt_all + (size_t)2 * 1024 * 1024 + (size_t)y0 * 1024;
        const unsigned short* Bp = Xb + (size_t)x0 * 1024;

        f32x4 acc[4][4] = {};

        for (int k0 = 0; k0 < 1024; k0 += 64) {
            #pragma unroll
            for (int c = 0; c < 4; c++) {
                int r = c * 32 + wave * 8 + srow;
                gload16(Ap + (size_t)r * 1024 + k0 + swz, &As[r * 64 + ch8]);
                gload16(Bp + (size_t)r * 1024 + k0 + swz, &Bs0[r * 64 + ch8]);
            }
            WAIT0_BARRIER();
            #pragma unroll
            for (int kk = 0; kk < 2; kk++) {
                bf16x8 af[4], bfr[4];
                #pragma unroll
                for (int i = 0; i < 4; i++)
                    af[i] = *(const bf16x8*)&As[(wrow + i * 16 + l15) * 64 +
                                                (((kk * 4 + quad) ^ sw)) * 8];
                #pragma unroll
                for (int j = 0; j < 4; j++)
                    bfr[j] = *(const bf16x8*)&Bs0[(wcol + j * 16 + l15) * 64 +
                                                  (((kk * 4 + quad) ^ sw)) * 8];
                #pragma unroll
                for (int i = 0; i < 4; i++)
                    #pragma unroll
                    for (int j = 0; j < 4; j++)
                        acc[i][j] = __builtin_amdgcn_mfma_f32_16x16x32_bf16(
                            af[i], bfr[j], acc[i][j], 0, 0, 0);
            }
            __syncthreads();
        }

        #pragma unroll
        for (int i = 0; i < 4; i++)
            #pragma unroll
            for (int r = 0; r < 4; r++) {
                int rowd = y0 + wrow + i * 16 + quad * 4 + r;   // d_full 0..1023
                float brow = bv[rowd];
                #pragma unroll
                for (int j = 0; j < 4; j++) {
                    int colm = x0 + wcol + j * 16 + l15;        // m 0..4095
                    int b = colm >> 11, s = colm & 2047;
                    Vt[(size_t)(b * 1024 + rowd) * 2048 + s] = f2bf(acc[i][j][r] + brow);
                }
            }
    }
}

// ---------------- flash attention (fixed-max, split-T) ---------------------
// 128 Q rows/block, 4 waves x 32 rows (mi=2). l via MFMA ones-column.
// Sync K/V staging (35 KB LDS -> 4 blocks/CU; r6-measured best).
__global__ __launch_bounds__(256) void attn_kernel(
    const unsigned short* __restrict__ Qb, const unsigned short* __restrict__ Kb,
    const unsigned short* __restrict__ Vt, unsigned short* __restrict__ Cc,
    float* __restrict__ Op, float* __restrict__ Lp, int tlen, int do_split) {
    const int bh = blockIdx.y;            // 0..31
    const int b = bh >> 4, h = bh & 15;
    const int q0 = blockIdx.x * 128;
    const int split = blockIdx.z;
    const int tbeg = split * tlen;

    const int tid = threadIdx.x;
    const int lane = tid & 63, wave = tid >> 6;
    const int quad = lane >> 4, l15 = lane & 15;

    __shared__ __align__(16) unsigned short Ks[64 * 64];
    __shared__ __align__(16) unsigned short Vs[64 * 64];
    __shared__ __align__(16) unsigned short Ps[4][32 * LDKP];

    const unsigned short* Qbh = Qb + (size_t)bh * 2048 * 64;
    const unsigned short* Kbh = Kb + (size_t)bh * 2048 * 64;
    const unsigned short* Vbh = Vt + (size_t)bh * 64 * 2048;

    // Q fragments in registers: A-layout m=lane&15, k=quad*8+j (m120)
    bf16x8 qa[2][2];
    #pragma unroll
    for (int mi = 0; mi < 2; mi++)
        #pragma unroll
        for (int kk = 0; kk < 2; kk++)
            qa[mi][kk] = *(const bf16x8*)&Qbh[
                (size_t)(q0 + wave * 32 + mi * 16 + l15) * 64 + kk * 32 + quad * 8];

    union { unsigned short us[8]; bf16x8 v; } ones_u;
    #pragma unroll
    for (int i = 0; i < 8; i++) ones_u.us[i] = 0x3F80;
    const bf16x8 onesv = ones_u.v;

    f32x4 o[2][4] = {};
    f32x4 ol[2] = {};

    const int srow = lane >> 3;                 // 0..7
    const int r0s = wave * 16 + srow;           // staging rows (2 per lane)
    const int ch8 = (lane & 7) * 8;
    const int swz = (((lane & 7) ^ srow)) * 8;  // row&7 == srow for both rows
    const int sw  = (l15 & 7);

    for (int ti = 0; ti < tlen; ti += 64) {
        const int t0 = tbeg + ti;
        __syncthreads();
        gload16(&Kbh[(size_t)(t0 + r0s) * 64 + swz],       &Ks[r0s * 64 + ch8]);
        gload16(&Kbh[(size_t)(t0 + r0s + 8) * 64 + swz],   &Ks[(r0s + 8) * 64 + ch8]);
        gload16(&Vbh[(size_t)r0s * 2048 + t0 + swz],       &Vs[r0s * 64 + ch8]);
        gload16(&Vbh[(size_t)(r0s + 8) * 2048 + t0 + swz], &Vs[(r0s + 8) * 64 + ch8]);
        asm volatile("s_waitcnt vmcnt(0)" ::: "memory");
        __syncthreads();

        // S = Q K^T (log2 domain), both mi share each kf read
        f32x4 sf[2][4] = {};
        #pragma unroll
        for (int j = 0; j < 4; j++)
            #pragma unroll
            for (int kk = 0; kk < 2; kk++) {
                bf16x8 kf = *(const bf16x8*)&Ks[(j * 16 + l15) * 64 +
                                                (((kk * 4 + quad) ^ sw)) * 8];
                sf[0][j] = __builtin_amdgcn_mfma_f32_16x16x32_bf16(qa[0][kk], kf, sf[0][j], 0, 0, 0);
                sf[1][j] = __builtin_amdgcn_mfma_f32_16x16x32_bf16(qa[1][kk], kf, sf[1][j], 0, 0, 0);
            }

        // P = exp2(S), truncated bf16, staged to LDS (C->A layout transform)
        #pragma unroll
        for (int mi = 0; mi < 2; mi++)
            #pragma unroll
            for (int j = 0; j < 4; j++)
                #pragma unroll
                for (int r = 0; r < 4; r++) {
                    float p = EXPFN(sf[mi][j][r]);
                    Ps[wave][(mi * 16 + quad * 4 + r) * LDKP + j * 16 + l15] =
                        (unsigned short)(__float_as_uint(p) >> 16);
                }

        asm volatile("s_waitcnt lgkmcnt(0)" ::: "memory");  // P visible wave-wide

        // O += P V ; l += P @ ones  (vf shared across mi)
        #pragma unroll
        for (int kk = 0; kk < 2; kk++) {
            bf16x8 pf0 = *(const bf16x8*)&Ps[wave][(l15) * LDKP + kk * 32 + quad * 8];
            bf16x8 pf1 = *(const bf16x8*)&Ps[wave][(16 + l15) * LDKP + kk * 32 + quad * 8];
            ol[0] = __builtin_amdgcn_mfma_f32_16x16x32_bf16(pf0, onesv, ol[0], 0, 0, 0);
            ol[1] = __builtin_amdgcn_mfma_f32_16x16x32_bf16(pf1, onesv, ol[1], 0, 0, 0);
            #pragma unroll
            for (int j = 0; j < 4; j++) {
                bf16x8 vf = *(const bf16x8*)&Vs[(j * 16 + l15) * 64 +
                                                (((kk * 4 + quad) ^ sw)) * 8];
                o[0][j] = __builtin_amdgcn_mfma_f32_16x16x32_bf16(pf0, vf, o[0][j], 0, 0, 0);
                o[1][j] = __builtin_amdgcn_mfma_f32_16x16x32_bf16(pf1, vf, o[1][j], 0, 0, 0);
            }
        }
    }

    if (do_split) {
        float* Opd = Op + (size_t)(split * 32 + bh) * 2048 * 64;
        float* Lpd = Lp + (size_t)(split * 32 + bh) * 2048;
        #pragma unroll
        for (int mi = 0; mi < 2; mi++)
            #pragma unroll
            for (int r = 0; r < 4; r++) {
                int s = q0 + wave * 32 + mi * 16 + quad * 4 + r;
                if (l15 == 0) Lpd[s] = ol[mi][r];
                #pragma unroll
                for (int j = 0; j < 4; j++)
                    Opd[(size_t)s * 64 + j * 16 + l15] = o[mi][j][r];
            }
    } else {
        #pragma unroll
        for (int mi = 0; mi < 2; mi++)
            #pragma unroll
            for (int r = 0; r < 4; r++) {
                float inv = 1.f / ol[mi][r];
                int s = q0 + wave * 32 + mi * 16 + quad * 4 + r;
                size_t row = (size_t)(b * 2048 + s);
                #pragma unroll
                for (int j = 0; j < 4; j++)
                    Cc[row * 1024 + h * 64 + j * 16 + l15] = f2bf(o[mi][j][r] * inv);
            }
    }
}

// ---------------- combine split partials -> Cc bf16 ------------------------
__global__ __launch_bounds__(256) void combine_kernel(
    const float4* __restrict__ Op, const float* __restrict__ Lp,
    unsigned short* __restrict__ Cc) {
    int idx = blockIdx.x * 256 + threadIdx.x;       // 0 .. 32*2048*16-1
    int d4 = idx & 15;
    int s = (idx >> 4) & 2047;
    int bh = idx >> 15;
    const size_t half4 = (size_t)32 * 2048 * 16;
    float4 a = Op[(size_t)idx], c = Op[half4 + (size_t)idx];
    float l = Lp[bh * 2048 + s] + Lp[32 * 2048 + bh * 2048 + s];
    float inv = 1.f / l;
    ushort4 o;
    o.x = f2bf((a.x + c.x) * inv); o.y = f2bf((a.y + c.y) * inv);
    o.z = f2bf((a.z + c.z) * inv); o.w = f2bf((a.w + c.w) * inv);
    int b = bh >> 4, h = bh & 15;
    *(ushort4*)&Cc[((size_t)(b * 2048 + s)) * 1024 + h * 64 + d4 * 4] = o;
}

// ---------------- output projection (128x64 tile, single-buffer) -----------
// grid (32,16) = 512 blocks = 2/CU; LDS 24 KB; wave tile 64x32.
__global__ __launch_bounds__(256) void gemm_out_kernel(
    const unsigned short* __restrict__ Cc, const unsigned short* __restrict__ Wot,
    const float* __restrict__ bo, float* __restrict__ out) {
    const int m0 = blockIdx.x * 128;   // over 4096
    const int n0 = blockIdx.y * 64;    // over 1024

    __shared__ __align__(16) unsigned short As[128 * 64];
    __shared__ __align__(16) unsigned short Bs[64 * 64];

    const int tid = threadIdx.x;
    const int lane = tid & 63, wave = tid >> 6;
    const int quad = lane >> 4, l15 = lane & 15;
    const int wrow = (wave >> 1) * 64, wcol = (wave & 1) * 32;

    f32x4 acc[4][2] = {};
    const int srow = lane >> 3;
    const int ch8 = (lane & 7) * 8;
    const int swz = (((lane & 7) ^ srow)) * 8;
    const int sw  = (l15 & 7);

    for (int k0 = 0; k0 < 1024; k0 += 64) {
        #pragma unroll
        for (int c = 0; c < 4; c++) {
            int r = c * 32 + wave * 8 + srow;
            gload16(Cc + (size_t)(m0 + r) * 1024 + k0 + swz, &As[r * 64 + ch8]);
            if (c < 2)
                gload16(Wot + (size_t)(n0 + r) * 1024 + k0 + swz, &Bs[r * 64 + ch8]);
        }
        WAIT0_BARRIER();
        #pragma unroll
        for (int kk = 0; kk < 2; kk++) {
            bf16x8 af[4], bfr[2];
            #pragma unroll
            for (int i = 0; i < 4; i++)
                af[i] = *(const bf16x8*)&As[(wrow + i * 16 + l15) * 64 +
                                            (((kk * 4 + quad) ^ sw)) * 8];
            #pragma unroll
            for (int j = 0; j < 2; j++)
                bfr[j] = *(const bf16x8*)&Bs[(wcol + j * 16 + l15) * 64 +
                                             (((kk * 4 + quad) ^ sw)) * 8];
            #pragma unroll
            for (int i = 0; i < 4; i++)
                #pragma unroll
                for (int j = 0; j < 2; j++)
                    acc[i][j] = __builtin_amdgcn_mfma_f32_16x16x32_bf16(
                        af[i], bfr[j], acc[i][j], 0, 0, 0);
        }
        __syncthreads();
    }

    #pragma unroll
    for (int j = 0; j < 2; j++) {
        int col = n0 + wcol + j * 16 + l15;
        float bcol = bo[col];
        #pragma unroll
        for (int i = 0; i < 4; i++)
            #pragma unroll
            for (int r = 0; r < 4; r++) {
                int row = m0 + wrow + i * 16 + quad * 4 + r;
                out[(size_t)row * 1024 + col] = acc[i][j][r] + bcol;
            }
    }
}

// ---------------------------------------------------------------------------
extern "C" void kernel_launch(void* const* d_in, const int* in_sizes, int n_in,
                              void* d_out, int out_size, void* d_ws, size_t ws_size,
                              hipStream_t stream) {
    const float* X  = (const float*)d_in[0];
    const float* Wq = (const float*)d_in[1];
    const float* bq = (const float*)d_in[2];
    const float* Wk = (const float*)d_in[3];
    const float* bk = (const float*)d_in[4];
    const float* Wv = (const float*)d_in[5];
    const float* bv = (const float*)d_in[6];
    const float* Wo = (const float*)d_in[7];
    const float* bo = (const float*)d_in[8];
    float* out = (float*)d_out;

    char* ws = (char*)d_ws;
    unsigned short* Xb = (unsigned short*)(ws);                    //  8 MB
    unsigned short* Wt = (unsigned short*)(ws + (8u  << 20));      //  8 MB (4 mats)
    unsigned short* Qb = (unsigned short*)(ws + (16u << 20));      //  8 MB
    unsigned short* Kb = (unsigned short*)(ws + (24u << 20));      //  8 MB
    unsigned short* Vt = (unsigned short*)(ws + (32u << 20));      //  8 MB
    unsigned short* Cc = (unsigned short*)(ws + (40u << 20));      //  8 MB
    float* Op = (float*)(ws + (48u << 20));                        // 32 MB
    float* Lp = (float*)(ws + (48u << 20) + 33554432u);            // 512 KB
    const bool use_split = ws_size >= ((size_t)(48u << 20) + 33554432u + 524288u);

    prep_kernel<<<dim3(32, 32, 5), 256, 0, stream>>>(X, (ushort4*)Xb, Wq, Wk, Wv, Wo, Wt);
    gemm_qkv_kernel<<<dim3(32, 8, 2), 256, 0, stream>>>(Xb, Wt, bq, bk, bv, Qb, Kb, Vt);
    if (use_split) {
        attn_kernel<<<dim3(16, 32, 2), 256, 0, stream>>>(Qb, Kb, Vt, Cc, Op, Lp, 1024, 1);
        combine_kernel<<<4096, 256, 0, stream>>>((const float4*)Op, Lp, Cc);
    } else {
        attn_kernel<<<dim3(16, 32, 1), 256, 0, stream>>>(Qb, Kb, Vt, Cc, Op, Lp, 2048, 0);
    }
    gemm_out_kernel<<<dim3(32, 16), 256, 0, stream>>>(Cc, Wt + 3u * 1024 * 1024, bo, out);
}

// Round 10
// 192.591 us; speedup vs baseline: 1.1725x; 1.0123x over previous
//
#include <hip/hip_runtime.h>

// ---------------------------------------------------------------------------
// MultiHeadSelfAttention: B=2, S=2048, D=1024, H=16, HD=64, fp32 in/out.
// prep (cast X + transpose W) -> 3-way fused QKV GEMM (one block computes
// Q,K,V tiles sharing a single A-stage; 48 MFMA / 10 gloads per iter; V^T
// produced via epilogue LDS transpose) -> split-T flash attention (fixed-max
// softmax, 128-row Q blocks, sync K/V staging) -> combine -> out projection
// GEMM (128x64 single-buffer). mfma_f32_16x16x32_bf16, fp32 accum.
// XOR swizzle: LDS rows are 64 shorts (128 B); chunk c (16 B) of row r holds
// global chunk c^(r&7). Staging permutes the GLOBAL address (global_load_lds
// dest must be base+lane*16); fragment reads apply the same permutation.
// ---------------------------------------------------------------------------

typedef __bf16 bf16x8 __attribute__((ext_vector_type(8)));
typedef float  f32x4  __attribute__((ext_vector_type(4)));

#if __has_builtin(__builtin_amdgcn_exp2f)
#define EXPFN(x) __builtin_amdgcn_exp2f(x)
#define QSCALE (0.125f * 1.44269504088896f)   // fold log2(e) into Q
#else
#define EXPFN(x) __expf(x)
#define QSCALE 0.125f
#endif

#define LDKP 74  // Ps leading dim (shorts): odd dword stride breaks collisions

__device__ __forceinline__ unsigned short f2bf(float f) {
    unsigned int u = __float_as_uint(f);
    u += 0x7FFFu + ((u >> 16) & 1u);   // RNE; finite inputs
    return (unsigned short)(u >> 16);
}

// async global->LDS, 16B per lane; HW dest = firstlane(lptr) + lane*16.
__device__ __forceinline__ void gload16(const void* g, void* l) {
    __builtin_amdgcn_global_load_lds(
        (const __attribute__((address_space(1))) void*)g,
        (__attribute__((address_space(3))) void*)l, 16, 0, 0);
}

#define WAIT0_BARRIER() asm volatile("s_waitcnt vmcnt(0)\n\ts_barrier" ::: "memory")

// ---------------- prep: cast X (z=4) + transpose/cast W (z=0..3) -----------
__global__ __launch_bounds__(256) void prep_kernel(
    const float* __restrict__ X, ushort4* __restrict__ Xb,
    const float* __restrict__ Wq, const float* __restrict__ Wk,
    const float* __restrict__ Wv, const float* __restrict__ Wo,
    unsigned short* __restrict__ Wt_all) {
    const int z = blockIdx.z;
    if (z == 4) {
        int base = (blockIdx.y * 32 + blockIdx.x) * 1024 + threadIdx.x;
        const float4* X4 = (const float4*)X;
        #pragma unroll
        for (int c = 0; c < 4; c++) {
            int i = base + c * 256;
            float4 v = X4[i];
            ushort4 o;
            o.x = f2bf(v.x); o.y = f2bf(v.y); o.z = f2bf(v.z); o.w = f2bf(v.w);
            Xb[i] = o;
        }
        return;
    }
    __shared__ float tile[32][33];
    const float* W = (z == 0) ? Wq : (z == 1) ? Wk : (z == 2) ? Wv : Wo;
    unsigned short* Wt = Wt_all + (size_t)z * 1024 * 1024;
    int c0 = blockIdx.x * 32, r0 = blockIdx.y * 32;
    int x = threadIdx.x & 31, y = threadIdx.x >> 5;   // (32, 8)
    for (int j = 0; j < 32; j += 8)
        tile[y + j][x] = W[(r0 + y + j) * 1024 + c0 + x];
    __syncthreads();
    for (int j = 0; j < 32; j += 8)
        Wt[(c0 + y + j) * 1024 + r0 + x] = f2bf(tile[x][y + j]);
}

// ---------------- 3-way fused QKV GEMM (128x64 tile, BK=64) ----------------
// Per block: As = X rows [x0,x0+128) staged once; Bq/Bk/Bv = W rows
// [y0,y0+64). 48 MFMA / 10 gloads per iter. Grid (32,16) = 512 = 2/CU.
// Q -> Qb[B,H,S,64] (scaled), K -> Kb[B,H,S,64], V -> Vt[B,H,64,S] via
// epilogue LDS transpose (stride 136 shorts: 16B-aligned rows, 2-way banks).
__global__ __launch_bounds__(256, 2) void gemm_qkv_kernel(
    const unsigned short* __restrict__ Xb, const unsigned short* __restrict__ Wt_all,
    const float* __restrict__ bq, const float* __restrict__ bk,
    const float* __restrict__ bv,
    unsigned short* __restrict__ Qb, unsigned short* __restrict__ Kb,
    unsigned short* __restrict__ Vt) {
    const int x0 = blockIdx.x * 128;   // over 4096 (X rows / seq)
    const int y0 = blockIdx.y * 64;    // over 1024 (W rows / out cols)

    __shared__ __align__(16) unsigned short smem[128 * 64 + 3 * 64 * 64]; // 40 KB
    unsigned short* As  = smem;             // 128x64
    unsigned short* Bqs = smem + 8192;      // 64x64
    unsigned short* Bks = smem + 12288;     // 64x64
    unsigned short* Bvs = smem + 16384;     // 64x64

    const unsigned short* Ap  = Xb + (size_t)x0 * 1024;
    const unsigned short* Bqp = Wt_all + (size_t)y0 * 1024;
    const unsigned short* Bkp = Wt_all + 1048576u + (size_t)y0 * 1024;
    const unsigned short* Bvp = Wt_all + 2097152u + (size_t)y0 * 1024;

    const int tid = threadIdx.x;
    const int lane = tid & 63, wave = tid >> 6;
    const int quad = lane >> 4, l15 = lane & 15;
    const int wrow = (wave >> 1) * 64, wcol = (wave & 1) * 32;

    f32x4 aq[4][2] = {};
    f32x4 ak[4][2] = {};
    f32x4 av[4][2] = {};

    const int srow = lane >> 3;            // 0..7
    const int ch8  = (lane & 7) * 8;       // natural chunk offset (shorts)
    const int swz  = (((lane & 7) ^ srow)) * 8;  // swizzled source chunk
    const int sw   = (l15 & 7);            // read-side row swizzle key

    for (int k0 = 0; k0 < 1024; k0 += 64) {
        #pragma unroll
        for (int c = 0; c < 4; c++) {
            int r = c * 32 + wave * 8 + srow;
            gload16(Ap + (size_t)r * 1024 + k0 + swz, &As[r * 64 + ch8]);
        }
        #pragma unroll
        for (int c = 0; c < 2; c++) {
            int r = c * 32 + wave * 8 + srow;
            gload16(Bqp + (size_t)r * 1024 + k0 + swz, &Bqs[r * 64 + ch8]);
            gload16(Bkp + (size_t)r * 1024 + k0 + swz, &Bks[r * 64 + ch8]);
            gload16(Bvp + (size_t)r * 1024 + k0 + swz, &Bvs[r * 64 + ch8]);
        }
        WAIT0_BARRIER();
        #pragma unroll
        for (int kk = 0; kk < 2; kk++) {
            bf16x8 af[4], bqf[2], bkf[2], bvf[2];
            const int co = (((kk * 4 + quad) ^ sw)) * 8;
            #pragma unroll
            for (int i = 0; i < 4; i++)
                af[i] = *(const bf16x8*)&As[(wrow + i * 16 + l15) * 64 + co];
            #pragma unroll
            for (int j = 0; j < 2; j++) {
                bqf[j] = *(const bf16x8*)&Bqs[(wcol + j * 16 + l15) * 64 + co];
                bkf[j] = *(const bf16x8*)&Bks[(wcol + j * 16 + l15) * 64 + co];
                bvf[j] = *(const bf16x8*)&Bvs[(wcol + j * 16 + l15) * 64 + co];
            }
            #pragma unroll
            for (int i = 0; i < 4; i++)
                #pragma unroll
                for (int j = 0; j < 2; j++) {
                    aq[i][j] = __builtin_amdgcn_mfma_f32_16x16x32_bf16(
                        af[i], bqf[j], aq[i][j], 0, 0, 0);
                    ak[i][j] = __builtin_amdgcn_mfma_f32_16x16x32_bf16(
                        af[i], bkf[j], ak[i][j], 0, 0, 0);
                    av[i][j] = __builtin_amdgcn_mfma_f32_16x16x32_bf16(
                        af[i], bvf[j], av[i][j], 0, 0, 0);
                }
        }
        __syncthreads();
    }

    // Q/K epilogue (registers only). C/D: col=lane&15, row=quad*4+reg.
    #pragma unroll
    for (int j = 0; j < 2; j++) {
        int col = y0 + wcol + j * 16 + l15;
        float bqc = bq[col], bkc = bk[col];
        int h = col >> 6, d = col & 63;
        #pragma unroll
        for (int i = 0; i < 4; i++)
            #pragma unroll
            for (int r = 0; r < 4; r++) {
                int row = x0 + wrow + i * 16 + quad * 4 + r;
                int b = row >> 11, s = row & 2047;
                size_t idx = (size_t)((b * 16 + h) * 2048 + s) * 64 + d;
                Qb[idx] = f2bf((aq[i][j][r] + bqc) * QSCALE);
                Kb[idx] = f2bf(ak[i][j][r] + bkc);
            }
    }

    // V epilogue: transpose through LDS, then coalesced V^T stores.
    __syncthreads();                        // staging smem now free
    unsigned short* vts = smem;             // 64 x 136 shorts (17.4 KB)
    #pragma unroll
    for (int j = 0; j < 2; j++) {
        int n = wcol + j * 16 + l15;        // 0..63 (d within tile)
        float bvc = bv[y0 + n];
        #pragma unroll
        for (int i = 0; i < 4; i++)
            #pragma unroll
            for (int r = 0; r < 4; r++) {
                int m = wrow + i * 16 + quad * 4 + r;   // 0..127 (seq in tile)
                vts[n * 136 + m] = f2bf(av[i][j][r] + bvc);
            }
    }
    __syncthreads();
    const int bseq = x0 >> 11;
    const int s0 = x0 & 2047;
    #pragma unroll
    for (int q = 0; q < 4; q++) {
        int c = q * 256 + tid;              // 0..1023 chunks of 16B
        int n = c >> 4, mc = c & 15;
        uint4 vv = *(const uint4*)&vts[n * 136 + mc * 8];
        *(uint4*)&Vt[(size_t)(bseq * 1024 + y0 + n) * 2048 + s0 + mc * 8] = vv;
    }
}

// ---------------- flash attention (fixed-max, split-T) ---------------------
// 128 Q rows/block, 4 waves x 32 rows (mi=2). l via MFMA ones-column.
// Sync K/V staging (35 KB LDS -> 4 blocks/CU; r6-measured best).
__global__ __launch_bounds__(256) void attn_kernel(
    const unsigned short* __restrict__ Qb, const unsigned short* __restrict__ Kb,
    const unsigned short* __restrict__ Vt, unsigned short* __restrict__ Cc,
    float* __restrict__ Op, float* __restrict__ Lp, int tlen, int do_split) {
    const int bh = blockIdx.y;            // 0..31
    const int b = bh >> 4, h = bh & 15;
    const int q0 = blockIdx.x * 128;
    const int split = blockIdx.z;
    const int tbeg = split * tlen;

    const int tid = threadIdx.x;
    const int lane = tid & 63, wave = tid >> 6;
    const int quad = lane >> 4, l15 = lane & 15;

    __shared__ __align__(16) unsigned short Ks[64 * 64];
    __shared__ __align__(16) unsigned short Vs[64 * 64];
    __shared__ __align__(16) unsigned short Ps[4][32 * LDKP];

    const unsigned short* Qbh = Qb + (size_t)bh * 2048 * 64;
    const unsigned short* Kbh = Kb + (size_t)bh * 2048 * 64;
    const unsigned short* Vbh = Vt + (size_t)bh * 64 * 2048;

    // Q fragments in registers: A-layout m=lane&15, k=quad*8+j (m120)
    bf16x8 qa[2][2];
    #pragma unroll
    for (int mi = 0; mi < 2; mi++)
        #pragma unroll
        for (int kk = 0; kk < 2; kk++)
            qa[mi][kk] = *(const bf16x8*)&Qbh[
                (size_t)(q0 + wave * 32 + mi * 16 + l15) * 64 + kk * 32 + quad * 8];

    union { unsigned short us[8]; bf16x8 v; } ones_u;
    #pragma unroll
    for (int i = 0; i < 8; i++) ones_u.us[i] = 0x3F80;
    const bf16x8 onesv = ones_u.v;

    f32x4 o[2][4] = {};
    f32x4 ol[2] = {};

    const int srow = lane >> 3;                 // 0..7
    const int r0s = wave * 16 + srow;           // staging rows (2 per lane)
    const int ch8 = (lane & 7) * 8;
    const int swz = (((lane & 7) ^ srow)) * 8;  // row&7 == srow for both rows
    const int sw  = (l15 & 7);

    for (int ti = 0; ti < tlen; ti += 64) {
        const int t0 = tbeg + ti;
        __syncthreads();
        gload16(&Kbh[(size_t)(t0 + r0s) * 64 + swz],       &Ks[r0s * 64 + ch8]);
        gload16(&Kbh[(size_t)(t0 + r0s + 8) * 64 + swz],   &Ks[(r0s + 8) * 64 + ch8]);
        gload16(&Vbh[(size_t)r0s * 2048 + t0 + swz],       &Vs[r0s * 64 + ch8]);
        gload16(&Vbh[(size_t)(r0s + 8) * 2048 + t0 + swz], &Vs[(r0s + 8) * 64 + ch8]);
        asm volatile("s_waitcnt vmcnt(0)" ::: "memory");
        __syncthreads();

        // S = Q K^T (log2 domain), both mi share each kf read
        f32x4 sf[2][4] = {};
        #pragma unroll
        for (int j = 0; j < 4; j++)
            #pragma unroll
            for (int kk = 0; kk < 2; kk++) {
                bf16x8 kf = *(const bf16x8*)&Ks[(j * 16 + l15) * 64 +
                                                (((kk * 4 + quad) ^ sw)) * 8];
                sf[0][j] = __builtin_amdgcn_mfma_f32_16x16x32_bf16(qa[0][kk], kf, sf[0][j], 0, 0, 0);
                sf[1][j] = __builtin_amdgcn_mfma_f32_16x16x32_bf16(qa[1][kk], kf, sf[1][j], 0, 0, 0);
            }

        // P = exp2(S), truncated bf16, staged to LDS (C->A layout transform)
        #pragma unroll
        for (int mi = 0; mi < 2; mi++)
            #pragma unroll
            for (int j = 0; j < 4; j++)
                #pragma unroll
                for (int r = 0; r < 4; r++) {
                    float p = EXPFN(sf[mi][j][r]);
                    Ps[wave][(mi * 16 + quad * 4 + r) * LDKP + j * 16 + l15] =
                        (unsigned short)(__float_as_uint(p) >> 16);
                }

        asm volatile("s_waitcnt lgkmcnt(0)" ::: "memory");  // P visible wave-wide

        // O += P V ; l += P @ ones  (vf shared across mi)
        #pragma unroll
        for (int kk = 0; kk < 2; kk++) {
            bf16x8 pf0 = *(const bf16x8*)&Ps[wave][(l15) * LDKP + kk * 32 + quad * 8];
            bf16x8 pf1 = *(const bf16x8*)&Ps[wave][(16 + l15) * LDKP + kk * 32 + quad * 8];
            ol[0] = __builtin_amdgcn_mfma_f32_16x16x32_bf16(pf0, onesv, ol[0], 0, 0, 0);
            ol[1] = __builtin_amdgcn_mfma_f32_16x16x32_bf16(pf1, onesv, ol[1], 0, 0, 0);
            #pragma unroll
            for (int j = 0; j < 4; j++) {
                bf16x8 vf = *(const bf16x8*)&Vs[(j * 16 + l15) * 64 +
                                                (((kk * 4 + quad) ^ sw)) * 8];
                o[0][j] = __builtin_amdgcn_mfma_f32_16x16x32_bf16(pf0, vf, o[0][j], 0, 0, 0);
                o[1][j] = __builtin_amdgcn_mfma_f32_16x16x32_bf16(pf1, vf, o[1][j], 0, 0, 0);
            }
        }
    }

    if (do_split) {
        float* Opd = Op + (size_t)(split * 32 + bh) * 2048 * 64;
        float* Lpd = Lp + (size_t)(split * 32 + bh) * 2048;
        #pragma unroll
        for (int mi = 0; mi < 2; mi++)
            #pragma unroll
            for (int r = 0; r < 4; r++) {
                int s = q0 + wave * 32 + mi * 16 + quad * 4 + r;
                if (l15 == 0) Lpd[s] = ol[mi][r];
                #pragma unroll
                for (int j = 0; j < 4; j++)
                    Opd[(size_t)s * 64 + j * 16 + l15] = o[mi][j][r];
            }
    } else {
        #pragma unroll
        for (int mi = 0; mi < 2; mi++)
            #pragma unroll
            for (int r = 0; r < 4; r++) {
                float inv = 1.f / ol[mi][r];
                int s = q0 + wave * 32 + mi * 16 + quad * 4 + r;
                size_t row = (size_t)(b * 2048 + s);
                #pragma unroll
                for (int j = 0; j < 4; j++)
                    Cc[row * 1024 + h * 64 + j * 16 + l15] = f2bf(o[mi][j][r] * inv);
            }
    }
}

// ---------------- combine split partials -> Cc bf16 ------------------------
__global__ __launch_bounds__(256) void combine_kernel(
    const float4* __restrict__ Op, const float* __restrict__ Lp,
    unsigned short* __restrict__ Cc) {
    int idx = blockIdx.x * 256 + threadIdx.x;       // 0 .. 32*2048*16-1
    int d4 = idx & 15;
    int s = (idx >> 4) & 2047;
    int bh = idx >> 15;
    const size_t half4 = (size_t)32 * 2048 * 16;
    float4 a = Op[(size_t)idx], c = Op[half4 + (size_t)idx];
    float l = Lp[bh * 2048 + s] + Lp[32 * 2048 + bh * 2048 + s];
    float inv = 1.f / l;
    ushort4 o;
    o.x = f2bf((a.x + c.x) * inv); o.y = f2bf((a.y + c.y) * inv);
    o.z = f2bf((a.z + c.z) * inv); o.w = f2bf((a.w + c.w) * inv);
    int b = bh >> 4, h = bh & 15;
    *(ushort4*)&Cc[((size_t)(b * 2048 + s)) * 1024 + h * 64 + d4 * 4] = o;
}

// ---------------- output projection (128x64 tile, single-buffer) -----------
// grid (32,16) = 512 blocks = 2/CU; LDS 24 KB; wave tile 64x32.
__global__ __launch_bounds__(256) void gemm_out_kernel(
    const unsigned short* __restrict__ Cc, const unsigned short* __restrict__ Wot,
    const float* __restrict__ bo, float* __restrict__ out) {
    const int m0 = blockIdx.x * 128;   // over 4096
    const int n0 = blockIdx.y * 64;    // over 1024

    __shared__ __align__(16) unsigned short As[128 * 64];
    __shared__ __align__(16) unsigned short Bs[64 * 64];

    const int tid = threadIdx.x;
    const int lane = tid & 63, wave = tid >> 6;
    const int quad = lane >> 4, l15 = lane & 15;
    const int wrow = (wave >> 1) * 64, wcol = (wave & 1) * 32;

    f32x4 acc[4][2] = {};
    const int srow = lane >> 3;
    const int ch8 = (lane & 7) * 8;
    const int swz = (((lane & 7) ^ srow)) * 8;
    const int sw  = (l15 & 7);

    for (int k0 = 0; k0 < 1024; k0 += 64) {
        #pragma unroll
        for (int c = 0; c < 4; c++) {
            int r = c * 32 + wave * 8 + srow;
            gload16(Cc + (size_t)(m0 + r) * 1024 + k0 + swz, &As[r * 64 + ch8]);
            if (c < 2)
                gload16(Wot + (size_t)(n0 + r) * 1024 + k0 + swz, &Bs[r * 64 + ch8]);
        }
        WAIT0_BARRIER();
        #pragma unroll
        for (int kk = 0; kk < 2; kk++) {
            bf16x8 af[4], bfr[2];
            #pragma unroll
            for (int i = 0; i < 4; i++)
                af[i] = *(const bf16x8*)&As[(wrow + i * 16 + l15) * 64 +
                                            (((kk * 4 + quad) ^ sw)) * 8];
            #pragma unroll
            for (int j = 0; j < 2; j++)
                bfr[j] = *(const bf16x8*)&Bs[(wcol + j * 16 + l15) * 64 +
                                             (((kk * 4 + quad) ^ sw)) * 8];
            #pragma unroll
            for (int i = 0; i < 4; i++)
                #pragma unroll
                for (int j = 0; j < 2; j++)
                    acc[i][j] = __builtin_amdgcn_mfma_f32_16x16x32_bf16(
                        af[i], bfr[j], acc[i][j], 0, 0, 0);
        }
        __syncthreads();
    }

    #pragma unroll
    for (int j = 0; j < 2; j++) {
        int col = n0 + wcol + j * 16 + l15;
        float bcol = bo[col];
        #pragma unroll
        for (int i = 0; i < 4; i++)
            #pragma unroll
            for (int r = 0; r < 4; r++) {
                int row = m0 + wrow + i * 16 + quad * 4 + r;
                out[(size_t)row * 1024 + col] = acc[i][j][r] + bcol;
            }
    }
}

// ---------------------------------------------------------------------------
extern "C" void kernel_launch(void* const* d_in, const int* in_sizes, int n_in,
                              void* d_out, int out_size, void* d_ws, size_t ws_size,
                              hipStream_t stream) {
    const float* X  = (const float*)d_in[0];
    const float* Wq = (const float*)d_in[1];
    const float* bq = (const float*)d_in[2];
    const float* Wk = (const float*)d_in[3];
    const float* bk = (const float*)d_in[4];
    const float* Wv = (const float*)d_in[5];
    const float* bv = (const float*)d_in[6];
    const float* Wo = (const float*)d_in[7];
    const float* bo = (const float*)d_in[8];
    float* out = (float*)d_out;

    char* ws = (char*)d_ws;
    unsigned short* Xb = (unsigned short*)(ws);                    //  8 MB
    unsigned short* Wt = (unsigned short*)(ws + (8u  << 20));      //  8 MB (4 mats)
    unsigned short* Qb = (unsigned short*)(ws + (16u << 20));      //  8 MB
    unsigned short* Kb = (unsigned short*)(ws + (24u << 20));      //  8 MB
    unsigned short* Vt = (unsigned short*)(ws + (32u << 20));      //  8 MB
    unsigned short* Cc = (unsigned short*)(ws + (40u << 20));      //  8 MB
    float* Op = (float*)(ws + (48u << 20));                        // 32 MB
    float* Lp = (float*)(ws + (48u << 20) + 33554432u);            // 512 KB
    const bool use_split = ws_size >= ((size_t)(48u << 20) + 33554432u + 524288u);

    prep_kernel<<<dim3(32, 32, 5), 256, 0, stream>>>(X, (ushort4*)Xb, Wq, Wk, Wv, Wo, Wt);
    gemm_qkv_kernel<<<dim3(32, 16), 256, 0, stream>>>(Xb, Wt, bq, bk, bv, Qb, Kb, Vt);
    if (use_split) {
        attn_kernel<<<dim3(16, 32, 2), 256, 0, stream>>>(Qb, Kb, Vt, Cc, Op, Lp, 1024, 1);
        combine_kernel<<<4096, 256, 0, stream>>>((const float4*)Op, Lp, Cc);
    } else {
        attn_kernel<<<dim3(16, 32, 1), 256, 0, stream>>>(Qb, Kb, Vt, Cc, Op, Lp, 2048, 0);
    }
    gemm_out_kernel<<<dim3(32, 16), 256, 0, stream>>>(Cc, Wt + 3u * 1024 * 1024, bo, out);
}